// Round 4
// baseline (4252.282 us; speedup 1.0000x reference)
//
#include <hip/hip_runtime.h>
#include <hip/hip_bf16.h>

// ---------------------------------------------------------------------------
// B=2,S=2048,D=1024; M=4096 rows. N_QK=N_V=4096, N_KNOW=8192.
// One fused GEMM over N=16384 (qk|v|know), bf16x4 split, 32x32x16 MFMA.
// This round:
//  - GEMM v5: staging-traffic-bound fix. Block tile 256x512 (8 waves, wave
//    tile 128x128, acc[4][4]), BK=16, 96KB dbuf LDS. Staged bytes 2.0->1.5GB.
//    New BK=16 swizzle: slot = seg ^ ((r>>1)&3) (4 slots of 16B per row),
//    read offset so = (h ^ ((l32>>1)&3))*16, L at so^32. 4-way conflicts.
//    Per-element accumulation order unchanged -> scores BIT-IDENTICAL.
//  - gate_all: exact pivot filter (mu+2sigma, exact count check, fallback)
//    kills the radix round-0 LDS-atomic histogram storm (67M -> ~2M atomics).
//    vk unchanged -> outputs BIT-IDENTICAL.
// ---------------------------------------------------------------------------

#define M_ROWS 4096
#define DIM    1024
#define N_QK   4096
#define N_KNOW 8192

typedef unsigned short ushortT;
typedef __attribute__((ext_vector_type(8)))  short short8;   // 8 bf16 (4 VGPR)
typedef __attribute__((ext_vector_type(16))) float f32x16;

// ---------------------------------------------------------------------------
// tau kernel
// ---------------------------------------------------------------------------
__global__ __launch_bounds__(256) void tau_kernel(
    const float* __restrict__ x, const float* __restrict__ w_attn,
    const float* __restrict__ b_attn, const float* __restrict__ w_know,
    const float* __restrict__ b_know, float* __restrict__ tau4, int D)
{
    __shared__ float s_f[4][4];
    const int row = blockIdx.x;
    const int tid = threadIdx.x;
    const float* xr = x + (size_t)row * D;
    float p0 = 0.f, p1 = 0.f, p2 = 0.f, p3 = 0.f;
    for (int d = tid; d < D; d += 256) {
        float xv = xr[d];
        p0 += xv * w_attn[d * 3 + 0];
        p1 += xv * w_attn[d * 3 + 1];
        p2 += xv * w_attn[d * 3 + 2];
        p3 += xv * w_know[d];
    }
#pragma unroll
    for (int o = 32; o > 0; o >>= 1) {
        p0 += __shfl_down(p0, o, 64);
        p1 += __shfl_down(p1, o, 64);
        p2 += __shfl_down(p2, o, 64);
        p3 += __shfl_down(p3, o, 64);
    }
    const int lane = tid & 63, wv = tid >> 6;
    if (lane == 0) { s_f[wv][0] = p0; s_f[wv][1] = p1; s_f[wv][2] = p2; s_f[wv][3] = p3; }
    __syncthreads();
    if (tid < 4) {
        float v = s_f[0][tid] + s_f[1][tid] + s_f[2][tid] + s_f[3][tid];
        v += (tid < 3) ? b_attn[tid] : b_know[0];
        tau4[(size_t)row * 4 + tid] = v;
    }
}

// ---------------------------------------------------------------------------
// split4: one float4 -> 4 bf16 hi (8B) + 4 bf16 lo (8B). Bit-identical to
// previous rounds (__float2bfloat16 RNE; residual exact in fp32).
// ---------------------------------------------------------------------------
__device__ __forceinline__ void split4(const float4 v, uint2& H, uint2& L) {
    float vv[4] = {v.x, v.y, v.z, v.w};
    unsigned h[4], l[4];
#pragma unroll
    for (int i = 0; i < 4; i++) {
        __hip_bfloat16 hb = __float2bfloat16(vv[i]);
        float r = vv[i] - __bfloat162float(hb);
        __hip_bfloat16 lb = __float2bfloat16(r);
        h[i] = *(ushortT*)&hb;
        l[i] = *(ushortT*)&lb;
    }
    H.x = h[0] | (h[1] << 16); H.y = h[2] | (h[3] << 16);
    L.x = l[0] | (l[1] << 16); L.y = l[2] | (l[3] << 16);
}

// ---------------------------------------------------------------------------
// convertA: rows x 1024 fp32 -> ext rows x [32 chunks][32 H | 32 L] bf16
// Row stride 2048 ushorts (4 KB). One float4 per thread. Used for A and B.
// ---------------------------------------------------------------------------
__global__ __launch_bounds__(256) void convertA(
    const float* __restrict__ src, ushortT* __restrict__ dst, int nElem4)
{
    int g = blockIdx.x * 256 + threadIdx.x;
    if (g >= nElem4) return;
    int row = g >> 8;            // 256 float4 per row
    int c4  = g & 255;           // float4 idx
    int chunk = c4 >> 3, pos = c4 & 7;
    const float4 v = *(const float4*)(src + (size_t)row * DIM + c4 * 4);
    uint2 H, L;
    split4(v, H, L);
    ushortT* base = dst + (size_t)row * 2048 + chunk * 64;
    *(uint2*)(base + pos * 4)      = H;
    *(uint2*)(base + 32 + pos * 4) = L;
}

// ---------------------------------------------------------------------------
// Fused GEMM v5: 512 threads / 8 waves, block tile 256x512, wave tile 128x128.
// BK=16 (half ext-chunk) phases, 96KB dynamic LDS double-buffer, one drain
// barrier per phase. Grid (nn, 16). Global n-block (512 cols) = nb0+blockIdx.x:
//   [0,8)=qk, [8,16)=v, [16,32)=know.
// ---------------------------------------------------------------------------
__global__ __launch_bounds__(512, 2) void gemm_fused5(
    const ushortT* __restrict__ Aext, const ushortT* __restrict__ Bext,
    float* __restrict__ gQ, float* __restrict__ gV, float* __restrict__ gKn,
    int nb0)
{
    extern __shared__ ushortT lds[];   // 2 x (A 8192 + B 16384 shorts) = 96 KB
#define ABUF(b) (lds + (b) * 24576)
#define BBUF(b) (lds + (b) * 24576 + 8192)
    const int tid = threadIdx.x;
    const int wave = tid >> 6, lane = tid & 63;
    const int l32 = lane & 31, h = lane >> 5;
    const int wm = (wave >> 2) * 128;      // 2 waves in M (256)
    const int wn = (wave & 3) * 128;       // 4 waves in N (512)
    const long long m0 = (long long)blockIdx.y * 256;
    const int nblk = nb0 + blockIdx.x;

    float* C; long long ldc; long long n0;
    if (nblk < 8)       { C = gQ;  ldc = N_QK;   n0 = (long long)nblk * 512; }
    else if (nblk < 16) { C = gV;  ldc = N_QK;   n0 = (long long)(nblk - 8) * 512; }
    else                { C = gKn; ldc = N_KNOW; n0 = (long long)(nblk - 16) * 512; }

    // staging plans: each row-phase is 4 slots of 16B; LDS slot sl holds
    // global seg sl ^ ((r>>1)&3)  (4-way-conflict-free read, see 'so')
    const ushortT* gAp[2]; int lA[2];
    const ushortT* gBp[4]; int lB[4];
#pragma unroll
    for (int it = 0; it < 2; ++it) {
        int f = it * 512 + tid;            // 0..1023 = 256 rows x 4 slots
        int r = f >> 2, sl = f & 3;
        int sg = sl ^ ((r >> 1) & 3);
        int sOff = ((sg & 2) << 4) + ((sg & 1) << 3);   // shorts within row-phase
        gAp[it] = Aext + (m0 + r) * 2048 + sOff;
        lA[it] = f * 8;                    // shorts (16B slots)
    }
#pragma unroll
    for (int it = 0; it < 4; ++it) {
        int f = it * 512 + tid;            // 0..2047 = 512 rows x 4 slots
        int r = f >> 2, sl = f & 3;
        int sg = sl ^ ((r >> 1) & 3);
        int sOff = ((sg & 2) << 4) + ((sg & 1) << 3);
        gBp[it] = Bext + ((long long)blockIdx.x * 512 + r) * 2048 + sOff;
        lB[it] = f * 8;
    }
    // read byte offset of my H seg within a row's 64B phase; L at so^32.
    const int so = (h ^ ((l32 >> 1) & 3)) * 16;

    f32x16 acc[4][4] = {};

#define STAGE(buf, cc) do {                                                        \
    const int cOff = ((cc) >> 1) * 64 + ((cc) & 1) * 16;   /* shorts */            \
    _Pragma("unroll")                                                              \
    for (int it = 0; it < 2; ++it)                                                 \
        __builtin_amdgcn_global_load_lds(                                          \
            (const __attribute__((address_space(1))) unsigned*)(const void*)(gAp[it] + cOff), \
            (__attribute__((address_space(3))) unsigned*)(void*)(ABUF(buf) + lA[it]), 16, 0, 0); \
    _Pragma("unroll")                                                              \
    for (int it = 0; it < 4; ++it)                                                 \
        __builtin_amdgcn_global_load_lds(                                          \
            (const __attribute__((address_space(1))) unsigned*)(const void*)(gBp[it] + cOff), \
            (__attribute__((address_space(3))) unsigned*)(void*)(BBUF(buf) + lB[it]), 16, 0, 0); \
} while (0)

#define COMPUTE(buf) do {                                                          \
    short8 aH[4], aL[4], bH[4], bL[4];                                             \
    _Pragma("unroll")                                                              \
    for (int t = 0; t < 4; ++t) {                                                  \
        const char* pa = (const char*)ABUF(buf) + (wm + t * 32 + l32) * 64;        \
        aH[t] = *(const short8*)(pa + so);                                         \
        aL[t] = *(const short8*)(pa + (so ^ 32));                                  \
        const char* pb = (const char*)BBUF(buf) + (wn + t * 32 + l32) * 64;        \
        bH[t] = *(const short8*)(pb + so);                                         \
        bL[t] = *(const short8*)(pb + (so ^ 32));                                  \
    }                                                                              \
    _Pragma("unroll")                                                              \
    for (int i = 0; i < 4; ++i)                                                    \
        _Pragma("unroll")                                                          \
        for (int j = 0; j < 4; ++j) {                                              \
            acc[i][j] = __builtin_amdgcn_mfma_f32_32x32x16_bf16(aH[i], bH[j], acc[i][j], 0, 0, 0); \
            acc[i][j] = __builtin_amdgcn_mfma_f32_32x32x16_bf16(aH[i], bL[j], acc[i][j], 0, 0, 0); \
            acc[i][j] = __builtin_amdgcn_mfma_f32_32x32x16_bf16(aL[i], bH[j], acc[i][j], 0, 0, 0); \
            acc[i][j] = __builtin_amdgcn_mfma_f32_32x32x16_bf16(aL[i], bL[j], acc[i][j], 0, 0, 0); \
        }                                                                          \
} while (0)

    // prologue: fill buf0 with phase 0
    STAGE(0, 0);
    __syncthreads();

    for (int cc = 0; cc < 64; cc += 2) {
        STAGE(1, cc + 1);             // prefetch next phase into other buffer
        COMPUTE(0);                   // 64 MFMAs/wave cover the DMA latency
        __syncthreads();              // drain AFTER compute
        if (cc + 2 < 64) STAGE(0, cc + 2);
        COMPUTE(1);
        __syncthreads();
    }
#undef STAGE
#undef COMPUTE
#undef ABUF
#undef BBUF

    // C/D: col=lane&31, row=(reg&3)+8*(reg>>2)+4*h  [m74/m101 verified]
#pragma unroll
    for (int ti = 0; ti < 4; ++ti)
#pragma unroll
        for (int tj = 0; tj < 4; ++tj) {
            long long col = n0 + wn + tj * 32 + l32;
            long long rb  = m0 + wm + ti * 32 + 4 * h;
#pragma unroll
            for (int reg = 0; reg < 16; ++reg) {
                long long row = rb + (reg & 3) + 8 * (reg >> 2);
                C[row * ldc + col] = acc[ti][tj][reg];
            }
        }
}

// ---------------------------------------------------------------------------
// OLD fused GEMM (fallback when ws cannot hold B_ext): unchanged, verified.
// ---------------------------------------------------------------------------
__global__ __launch_bounds__(256) void gemm_fused2(
    const ushortT* __restrict__ Aext, const float* __restrict__ qk_emb,
    const float* __restrict__ v_emb, const float* __restrict__ know_emb,
    float* __restrict__ gQ, float* __restrict__ gV, float* __restrict__ gKn,
    long long rowOff)
{
    __shared__ ushortT AHL[128 * 64];   // 128 rows x 128 B
    __shared__ ushortT BHL[128 * 64];
    const int tid = threadIdx.x;
    const int wave = tid >> 6, lane = tid & 63;
    const int l32 = lane & 31, h = lane >> 5;
    const int rx7 = l32 & 7;
    const int wm = (wave >> 1) * 64, wn = (wave & 1) * 64;
    const long long m0 = (long long)blockIdx.y * 128;
    const int nblk = blockIdx.x;

    const float* Bsrc; float* C; long long ldc; long long n0;
    if (nblk < 32)      { Bsrc = qk_emb;   C = gQ;  ldc = N_QK;   n0 = (long long)nblk * 128; }
    else if (nblk < 64) { Bsrc = v_emb;    C = gV;  ldc = N_QK;   n0 = (long long)(nblk - 32) * 128; }
    else                { Bsrc = know_emb; C = gKn; ldc = N_KNOW; n0 = (long long)(nblk - 64) * 128; }

    const ushortT* gAp[4]; ushortT* lAp[4];
    const float*   gBp[4]; int offH[4], offL[4];
#pragma unroll
    for (int it = 0; it < 4; ++it) {
        int f = it * 256 + tid;
        int r = f >> 3, sp = f & 7;
        int sg = sp ^ (r & 7);
        gAp[it] = Aext + (m0 + r) * 2048 + sg * 8;
        lAp[it] = AHL + f * 8;
        int c4 = f & 7;
        int s = c4 >> 1, hf = c4 & 1;
        offH[it] = r * 128 + ((s ^ (r & 7)) * 16) + hf * 8;
        offL[it] = r * 128 + (((4 | s) ^ (r & 7)) * 16) + hf * 8;
        gBp[it] = Bsrc + (n0 + r) * DIM + c4 * 4;
    }
    const char* pA[2]; const char* pB[2];
#pragma unroll
    for (int t = 0; t < 2; ++t) {
        pA[t] = (const char*)AHL + (wm + t * 32 + l32) * 128;
        pB[t] = (const char*)BHL + (wn + t * 32 + l32) * 128;
    }

    f32x16 acc[2][2] = {};
    float4 bufB[4];
#pragma unroll
    for (int it = 0; it < 4; ++it) bufB[it] = *(const float4*)(gBp[it]);

    for (int c = 0; c < 32; ++c) {
#pragma unroll
        for (int it = 0; it < 4; ++it) {
            __builtin_amdgcn_global_load_lds(
                (const __attribute__((address_space(1))) unsigned*)(const void*)(gAp[it] + c * 64),
                (__attribute__((address_space(3))) unsigned*)(void*)lAp[it], 16, 0, 0);
            uint2 H, L;
            split4(bufB[it], H, L);
            *(uint2*)((char*)BHL + offH[it]) = H;
            *(uint2*)((char*)BHL + offL[it]) = L;
        }
        __syncthreads();
        if (c + 1 < 32) {
#pragma unroll
            for (int it = 0; it < 4; ++it)
                bufB[it] = *(const float4*)(gBp[it] + (c + 1) * 32);
        }
#pragma unroll
        for (int kb = 0; kb < 2; ++kb) {
            const int so = ((kb * 2 + h) ^ rx7) * 16;
            short8 aH[2], aL[2], bH[2], bL[2];
#pragma unroll
            for (int t = 0; t < 2; ++t) {
                aH[t] = *(const short8*)(pA[t] + so);
                aL[t] = *(const short8*)(pA[t] + (so ^ 64));
                bH[t] = *(const short8*)(pB[t] + so);
                bL[t] = *(const short8*)(pB[t] + (so ^ 64));
            }
#pragma unroll
            for (int i = 0; i < 2; ++i)
#pragma unroll
                for (int j = 0; j < 2; ++j) {
                    acc[i][j] = __builtin_amdgcn_mfma_f32_32x32x16_bf16(aH[i], bH[j], acc[i][j], 0, 0, 0);
                    acc[i][j] = __builtin_amdgcn_mfma_f32_32x32x16_bf16(aH[i], bL[j], acc[i][j], 0, 0, 0);
                    acc[i][j] = __builtin_amdgcn_mfma_f32_32x32x16_bf16(aL[i], bH[j], acc[i][j], 0, 0, 0);
                    acc[i][j] = __builtin_amdgcn_mfma_f32_32x32x16_bf16(aL[i], bL[j], acc[i][j], 0, 0, 0);
                }
        }
        __syncthreads();
    }
#pragma unroll
    for (int ti = 0; ti < 2; ++ti)
#pragma unroll
        for (int tj = 0; tj < 2; ++tj) {
            long long col = n0 + wn + tj * 32 + l32;
            long long rb  = rowOff + m0 + wm + ti * 32 + 4 * h;
#pragma unroll
            for (int reg = 0; reg < 16; ++reg) {
                long long row = rb + (reg & 3) + 8 * (reg >> 2);
                C[row * ldc + col] = acc[ti][tj][reg];
            }
        }
}

// ---------------------------------------------------------------------------
// Gate body: keys in registers; exact k-th largest via 8-bit RADIX SELECT,
// with an exact pivot pre-filter (mu+2sigma; verified by exact count; falls
// back to unfiltered when count < k). Keys < pivot are all < kth, so the
// selected vk is EXACTLY the k-th largest key -> outputs bit-identical.
// ---------------------------------------------------------------------------
__device__ __forceinline__ unsigned floatToKey(float f) {
    unsigned b = __float_as_uint(f);
    return (b & 0x80000000u) ? ~b : (b | 0x80000000u);
}
__device__ __forceinline__ float keyToFloat(unsigned key) {
    unsigned b = (key & 0x80000000u) ? (key & 0x7FFFFFFFu) : ~key;
    return __uint_as_float(b);
}
__device__ __forceinline__ float egate(float raw) {
    float g = raw > 0.f ? raw : 1e-8f * __expf(raw);
    return expf(g) - 1.f;
}

template <int NV, bool VLOAD, bool VSTORE>
__device__ __forceinline__ void gate_body(
    const float* __restrict__ srow, float tA, float tB, bool hasB, int ksel,
    float* __restrict__ orowA, float* __restrict__ orowB,
    float* __restrict__ colA, float* __restrict__ colB,
    int* s_hist, unsigned* s_u, float* s_f)
{
    const int tid = threadIdx.x, lane = tid & 63, wv = tid >> 6;

    unsigned keys[NV * 4];
    unsigned kmax = 0u;
    float fs = 0.f, fq = 0.f;
#pragma unroll
    for (int i = 0; i < NV; i++) {
        float v0, v1, v2, v3;
        if (VLOAD) {
            float4 v = *(const float4*)(srow + (size_t)(i * 256 + tid) * 4);
            v0 = v.x; v1 = v.y; v2 = v.z; v3 = v.w;
        } else {
            v0 = srow[(i * 4 + 0) * 256 + tid];
            v1 = srow[(i * 4 + 1) * 256 + tid];
            v2 = srow[(i * 4 + 2) * 256 + tid];
            v3 = srow[(i * 4 + 3) * 256 + tid];
        }
        fs += v0 + v1 + v2 + v3;
        fq += v0 * v0 + v1 * v1 + v2 * v2 + v3 * v3;
        unsigned a = floatToKey(v0), b = floatToKey(v1);
        unsigned c = floatToKey(v2), d = floatToKey(v3);
        keys[i * 4 + 0] = a; keys[i * 4 + 1] = b;
        keys[i * 4 + 2] = c; keys[i * 4 + 3] = d;
        unsigned m1 = a > b ? a : b, m2 = c > d ? c : d;
        m1 = m1 > m2 ? m1 : m2;
        kmax = kmax > m1 ? kmax : m1;
    }
#pragma unroll
    for (int o = 32; o > 0; o >>= 1) {
        unsigned x = __shfl_down(kmax, o, 64);
        kmax = kmax > x ? kmax : x;
        fs += __shfl_down(fs, o, 64);
        fq += __shfl_down(fq, o, 64);
    }
    if (lane == 0) { s_u[wv] = kmax; s_f[wv] = fs; s_f[4 + wv] = fq; }
    __syncthreads();
    { unsigned a = s_u[0], b = s_u[1], c = s_u[2], d = s_u[3];
      unsigned m1 = a > b ? a : b, m2 = c > d ? c : d; kmax = m1 > m2 ? m1 : m2; }
    fs = s_f[0] + s_f[1] + s_f[2] + s_f[3];
    fq = s_f[4] + s_f[5] + s_f[6] + s_f[7];

    // exact pivot filter: piv = mu + 2*sigma (exact moments of this row)
    const float NT = (float)(NV * 4 * 256);
    const float mu = fs / NT;
    const float sd = sqrtf(fmaxf(fq / NT - mu * mu, 0.f));
    const unsigned pk = floatToKey(mu + 2.0f * sd);
    __syncthreads();                       // s_u/s_f reused below

    int pc = 0;
#pragma unroll
    for (int i = 0; i < NV * 4; i++) pc += (keys[i] >= pk) ? 1 : 0;
#pragma unroll
    for (int o = 32; o > 0; o >>= 1) pc += __shfl_down(pc, o, 64);
    if (lane == 0) s_u[wv] = (unsigned)pc;
    __syncthreads();
    const int ptot = (int)(s_u[0] + s_u[1] + s_u[2] + s_u[3]);
    const unsigned filt = (ptot >= ksel) ? pk : 0u;   // safe: filt <= kth key

    // ---- exact k-th largest key via 4-round radix select (filtered) ----
    unsigned prefix = 0u;
    int kk = ksel;
#pragma unroll
    for (int rnd = 0; rnd < 4; ++rnd) {
        const int sh = 24 - 8 * rnd;
        s_hist[tid] = 0;
        __syncthreads();
#pragma unroll
        for (int i = 0; i < NV * 4; i++) {
            unsigned key = keys[i];
            if (key >= filt && (((key ^ prefix) >> sh) >> 8) == 0u)
                atomicAdd(&s_hist[(key >> sh) & 255u], 1);
        }
        __syncthreads();
        if (tid < 64) {
            const int b3 = 255 - 4 * tid;          // lane covers bins b3-3..b3
            const int h0 = s_hist[b3],     h1 = s_hist[b3 - 1];
            const int h2 = s_hist[b3 - 2], h3 = s_hist[b3 - 3];
            const int gsum = h0 + h1 + h2 + h3;
            int inc = gsum;                         // inclusive scan, asc lane = desc bins
#pragma unroll
            for (int o = 1; o < 64; o <<= 1) {
                int v = __shfl_up(inc, o, 64);
                if (tid >= o) inc += v;
            }
            const int above = inc - gsum;           // keys in strictly higher bins
            const int c0 = above + h0, c1 = c0 + h1, c2 = c1 + h2, c3 = c2 + h3;
            if (kk > above && kk <= c3) {           // exactly one lane hits
                unsigned byt; int nk;
                if (kk <= c0)      { byt = (unsigned)b3;       nk = kk - above; }
                else if (kk <= c1) { byt = (unsigned)(b3 - 1); nk = kk - c0; }
                else if (kk <= c2) { byt = (unsigned)(b3 - 2); nk = kk - c1; }
                else               { byt = (unsigned)(b3 - 3); nk = kk - c2; }
                s_u[0] = byt; s_u[1] = (unsigned)nk;
            }
        }
        __syncthreads();
        prefix |= s_u[0] << sh;
        kk = (int)s_u[1];
    }
    const unsigned vk = prefix;                     // exact k-th largest key

    float sA = 0.f, sB = 0.f;
#pragma unroll
    for (int i = 0; i < NV * 4; i++) {
        if (keys[i] >= vk) {
            float s = keyToFloat(keys[i]);
            sA += egate(s - tA);
            if (hasB) sB += egate(s - tB);
        }
    }
#pragma unroll
    for (int o = 32; o > 0; o >>= 1) {
        sA += __shfl_down(sA, o, 64);
        sB += __shfl_down(sB, o, 64);
    }
    if (lane == 0) { s_f[wv] = sA; s_f[4 + wv] = sB; }
    __syncthreads();
    sA = s_f[0] + s_f[1] + s_f[2] + s_f[3];
    sB = s_f[4] + s_f[5] + s_f[6] + s_f[7];

    const float smax = keyToFloat(kmax);
    const float scaleA = tanhf(egate(smax - tA)) / (sA + 1e-8f);
    const float scaleB = hasB ? tanhf(egate(smax - tB)) / (sB + 1e-8f) : 0.f;

#pragma unroll
    for (int i = 0; i < NV; i++) {
        float ga[4], gb[4];
        int eidx[4];
#pragma unroll
        for (int j = 0; j < 4; j++) {
            int ii = i * 4 + j;
            int idx = VLOAD ? (i * 1024 + tid * 4 + j) : (ii * 256 + tid);
            eidx[j] = idx;
            unsigned key = keys[ii];
            float vA = 0.f, vB = 0.f;
            if (key >= vk) {
                float s = keyToFloat(key);
                vA = egate(s - tA) * scaleA;
                atomicAdd(&colA[idx], vA);
                if (hasB) { vB = egate(s - tB) * scaleB; atomicAdd(&colB[idx], vB); }
            }
            ga[j] = vA; gb[j] = vB;
        }
        if (VSTORE) {
            *(float4*)(orowA + (size_t)eidx[0]) = make_float4(ga[0], ga[1], ga[2], ga[3]);
            if (hasB) *(float4*)(orowB + (size_t)eidx[0]) = make_float4(gb[0], gb[1], gb[2], gb[3]);
        } else {
#pragma unroll
            for (int j = 0; j < 4; j++) {
                orowA[eidx[j]] = ga[j];
                if (hasB) orowB[eidx[j]] = gb[j];
            }
        }
    }
}

// Merged gate dispatch: [0,4096)=know, [4096,8192)=qk (Q+K), [8192,12288)=v
__global__ __launch_bounds__(256) void gate_all(
    const float* __restrict__ tau4,
    float* __restrict__ gQ, float* __restrict__ gK,
    float* __restrict__ gV, float* __restrict__ gKn,
    float* __restrict__ colsums)
{
    __shared__ int s_hist[256];
    __shared__ unsigned s_u[4];
    __shared__ float s_f[8];
    const int bid = blockIdx.x;
    if (bid < 4096) {
        const int row = bid;
        const float t = tau4[(size_t)row * 4 + 3];
        gate_body<8, false, false>(
            gKn + (size_t)row * N_KNOW, t, 0.f, false, 128,
            gKn + (size_t)row * N_KNOW, nullptr,
            colsums + 3 * N_QK, nullptr, s_hist, s_u, s_f);
    } else if (bid < 8192) {
        const int row = bid - 4096;
        const float tA = tau4[(size_t)row * 4 + 0];
        const float tB = tau4[(size_t)row * 4 + 1];
        gate_body<4, true, true>(
            gQ + (size_t)row * N_QK, tA, tB, true, 64,
            gQ + (size_t)row * N_QK, gK + (size_t)row * N_QK,
            colsums, colsums + N_QK, s_hist, s_u, s_f);
    } else {
        const int row = bid - 8192;
        const float t = tau4[(size_t)row * 4 + 2];
        gate_body<4, true, true>(
            gV + (size_t)row * N_QK, t, 0.f, false, 64,
            gV + (size_t)row * N_QK, nullptr,
            colsums + 2 * N_QK, nullptr, s_hist, s_u, s_f);
    }
}

// ---------------------------------------------------------------------------
// Aux kernel
// ---------------------------------------------------------------------------
__global__ __launch_bounds__(256) void aux_kernel(
    const float* __restrict__ colsum,
    float* __restrict__ auxAttn, float* __restrict__ auxKnow)
{
    __shared__ float s_a[4];
    __shared__ float s_b[4];
    const int tid = threadIdx.x;
    const int lane = tid & 63, wv = tid >> 6;
    const float invM = 1.f / 4096.f;

    float sa = 0.f;
    const float tqk = 1.f / 4096.f;
    for (int i = tid; i < 3 * N_QK; i += 256) {
        float m = colsum[i] * invM - tqk;
        sa += m * m;
    }
    float sk = 0.f;
    const float tkn = 1.f / 8192.f;
    for (int i = tid; i < N_KNOW; i += 256) {
        float m = colsum[3 * N_QK + i] * invM - tkn;
        sk += m * m;
    }
#pragma unroll
    for (int o = 32; o > 0; o >>= 1) {
        sa += __shfl_down(sa, o, 64);
        sk += __shfl_down(sk, o, 64);
    }
    if (lane == 0) { s_a[wv] = sa; s_b[wv] = sk; }
    __syncthreads();
    if (tid == 0) {
        auxAttn[0] = (s_a[0] + s_a[1] + s_a[2] + s_a[3]) * 4096.f;
        auxKnow[0] = (s_b[0] + s_b[1] + s_b[2] + s_b[3]) * 8192.f;
    }
}

// ---------------------------------------------------------------------------
// Host helper: convert B rows [rowLo,rowHi) of the concatenated (qk|v|know)
// matrix into Bext (local row 0 = global row rowLo).
// ---------------------------------------------------------------------------
static void convert_b_range(const float* qk, const float* v, const float* kn,
                            ushortT* Bext, long long rowLo, long long rowHi,
                            hipStream_t stream)
{
    struct Seg { const float* p; long long lo, hi; };
    Seg seg[3] = { {qk, 0, 4096}, {v, 4096, 8192}, {kn, 8192, 16384} };
    for (int i = 0; i < 3; ++i) {
        long long lo = rowLo > seg[i].lo ? rowLo : seg[i].lo;
        long long hi = rowHi < seg[i].hi ? rowHi : seg[i].hi;
        if (lo < hi) {
            int nel4 = (int)((hi - lo) * 256);
            convertA<<<(nel4 + 255) / 256, 256, 0, stream>>>(
                seg[i].p + (size_t)(lo - seg[i].lo) * DIM,
                Bext + (size_t)(lo - rowLo) * 2048, nel4);
        }
    }
}

// ---------------------------------------------------------------------------
// Launch
// ---------------------------------------------------------------------------
extern "C" void kernel_launch(void* const* d_in, const int* in_sizes, int n_in,
                              void* d_out, int out_size, void* d_ws, size_t ws_size,
                              hipStream_t stream)
{
    const float* x        = (const float*)d_in[0];
    const float* qk_emb   = (const float*)d_in[1];
    const float* v_emb    = (const float*)d_in[2];
    const float* know_emb = (const float*)d_in[3];
    const float* w_attn   = (const float*)d_in[4];
    const float* b_attn   = (const float*)d_in[5];
    const float* w_know   = (const float*)d_in[6];
    const float* b_know   = (const float*)d_in[7];
    float* out = (float*)d_out;

    const long long M = M_ROWS;

    float* gQ   = out;
    float* gK   = gQ + (size_t)M * N_QK;
    float* gV   = gK + (size_t)M * N_QK;
    float* auxA = gV + (size_t)M * N_QK;
    float* gKn  = auxA + 1;                    // only 4-byte aligned: scalar path
    float* auxK = gKn + (size_t)M * N_KNOW;

    // ---- ws plan: [A_ext][B_ext...][tau4|colsums] ----
    const long long nColsum = 3 * N_QK + N_KNOW;
    const long long tail_bytes = (M * 4 + nColsum) * 4;
    long long tailStart = ((long long)ws_size - tail_bytes) & ~255LL;
    float* tau4 = (float*)((char*)d_ws + tailStart);
    float* colsums = tau4 + (size_t)M * 4;

    const long long rowB = 4096;               // ext bytes per row
    const long long aBytes = M * rowB;         // 16 MB for full A_ext

    hipMemsetAsync(colsums, 0, nColsum * sizeof(float), stream);
    tau_kernel<<<(int)M, 256, 0, stream>>>(x, w_attn, b_attn, w_know, b_know, tau4, DIM);

    // B_ext capacity in units of 512-row n-blocks (2 MB each)
    long long availB = tailStart - aBytes;
    long long nbc = availB > 0 ? availB / (512 * rowB) : 0;
    if (nbc > 32) nbc = 32;

    if (nbc >= 8) {
        // ---- pre-split A and B, DMA-staged double-buffered GEMM (v5) ----
        ushortT* A_ext = (ushortT*)d_ws;
        ushortT* B_ext = (ushortT*)((char*)d_ws + aBytes);
        convertA<<<(int)(M * 256 / 256), 256, 0, stream>>>(x, A_ext, (int)(M * 256));
        for (long long nb0 = 0; nb0 < 32; nb0 += nbc) {
            long long nn = (32 - nb0 < nbc) ? (32 - nb0) : nbc;
            convert_b_range(qk_emb, v_emb, know_emb, B_ext,
                            nb0 * 512, (nb0 + nn) * 512, stream);
            gemm_fused5<<<dim3((unsigned)nn, 16), 512, 98304, stream>>>(
                A_ext, B_ext, gQ, gV, gKn, (int)nb0);
        }
    } else {
        // ---- fallback: A chunked, B split in-kernel ----
        long long ra = (tailStart / rowB / 128) * 128;
        if (ra > M) ra = M;
        if (ra < 128) ra = 128;
        ushortT* A_ext = (ushortT*)d_ws;
        for (long long a0 = 0; a0 < M; a0 += ra) {
            long long ac = (M - a0 < ra) ? (M - a0) : ra;
            int nel4 = (int)(ac * 256);
            convertA<<<(nel4 + 255) / 256, 256, 0, stream>>>(x + a0 * DIM, A_ext, nel4);
            gemm_fused2<<<dim3(128, (unsigned)(ac / 128)), 256, 0, stream>>>(
                A_ext, qk_emb, v_emb, know_emb, gQ, gV, gKn, a0);
        }
    }

    gate_all<<<12288, 256, 0, stream>>>(tau4, gQ, gK, gV, gKn, colsums);

    aux_kernel<<<1, 256, 0, stream>>>(colsums, auxA, auxK);
}

// Round 5
// 2453.412 us; speedup vs baseline: 1.7332x; 1.7332x over previous
//
#include <hip/hip_runtime.h>
#include <hip/hip_bf16.h>

// ---------------------------------------------------------------------------
// B=2,S=2048,D=1024; M=4096 rows. N_QK=N_V=4096, N_KNOW=8192.
// One fused GEMM over N=16384 (qk|v|know), bf16x4 split, 32x32x16 MFMA.
// Round 5 (fix of round-4 regression):
//  - Ext buffers re-laid out PHASE-MAJOR: [64 phases][rows][16H|16L] (64B/row
//    per phase). Staging one phase = contiguous 16KB (A) / 32KB (B) per block
//    -> full cache-line utilization (round-4's chunk-major split caused 4x
//    line waste + L2 thrash: FETCH 6.3GB, MfmaUtil 6%).
//  - LDS geometry/swizzle/read path identical to round-4 (verified bit-exact);
//    COMPUTE restructured per-j to cut live fragment VGPRs 64->40. Per-element
//    accumulation order unchanged (phase asc -> HH,HL,LH,LL) -> BIT-IDENTICAL.
//  - XCD-aware bijective swizzle: each XCD owns bx columns (B panels resident
//    in its L2 across the 16-y sweep).
//  - gate_all: round-4 pivot filter kept (verified).
// Fallback (ws too small): original chunk-major convertA + gemm_fused2.
// ---------------------------------------------------------------------------

#define M_ROWS 4096
#define DIM    1024
#define N_QK   4096
#define N_KNOW 8192

typedef unsigned short ushortT;
typedef __attribute__((ext_vector_type(8)))  short short8;   // 8 bf16 (4 VGPR)
typedef __attribute__((ext_vector_type(16))) float f32x16;

// ---------------------------------------------------------------------------
// tau kernel
// ---------------------------------------------------------------------------
__global__ __launch_bounds__(256) void tau_kernel(
    const float* __restrict__ x, const float* __restrict__ w_attn,
    const float* __restrict__ b_attn, const float* __restrict__ w_know,
    const float* __restrict__ b_know, float* __restrict__ tau4, int D)
{
    __shared__ float s_f[4][4];
    const int row = blockIdx.x;
    const int tid = threadIdx.x;
    const float* xr = x + (size_t)row * D;
    float p0 = 0.f, p1 = 0.f, p2 = 0.f, p3 = 0.f;
    for (int d = tid; d < D; d += 256) {
        float xv = xr[d];
        p0 += xv * w_attn[d * 3 + 0];
        p1 += xv * w_attn[d * 3 + 1];
        p2 += xv * w_attn[d * 3 + 2];
        p3 += xv * w_know[d];
    }
#pragma unroll
    for (int o = 32; o > 0; o >>= 1) {
        p0 += __shfl_down(p0, o, 64);
        p1 += __shfl_down(p1, o, 64);
        p2 += __shfl_down(p2, o, 64);
        p3 += __shfl_down(p3, o, 64);
    }
    const int lane = tid & 63, wv = tid >> 6;
    if (lane == 0) { s_f[wv][0] = p0; s_f[wv][1] = p1; s_f[wv][2] = p2; s_f[wv][3] = p3; }
    __syncthreads();
    if (tid < 4) {
        float v = s_f[0][tid] + s_f[1][tid] + s_f[2][tid] + s_f[3][tid];
        v += (tid < 3) ? b_attn[tid] : b_know[0];
        tau4[(size_t)row * 4 + tid] = v;
    }
}

// ---------------------------------------------------------------------------
// split4: one float4 -> 4 bf16 hi (8B) + 4 bf16 lo (8B). Bit-identical to
// previous rounds (__float2bfloat16 RNE; residual exact in fp32).
// ---------------------------------------------------------------------------
__device__ __forceinline__ void split4(const float4 v, uint2& H, uint2& L) {
    float vv[4] = {v.x, v.y, v.z, v.w};
    unsigned h[4], l[4];
#pragma unroll
    for (int i = 0; i < 4; i++) {
        __hip_bfloat16 hb = __float2bfloat16(vv[i]);
        float r = vv[i] - __bfloat162float(hb);
        __hip_bfloat16 lb = __float2bfloat16(r);
        h[i] = *(ushortT*)&hb;
        l[i] = *(ushortT*)&lb;
    }
    H.x = h[0] | (h[1] << 16); H.y = h[2] | (h[3] << 16);
    L.x = l[0] | (l[1] << 16); L.y = l[2] | (l[3] << 16);
}

// ---------------------------------------------------------------------------
// convertP: PHASE-MAJOR ext. src rows x 1024 fp32 ->
//   dst[p][rowOff+row][16H|16L] , p = k/16, 32 shorts (64B) per row-phase.
// One float4 per thread: phase p = c4>>2, offset o = c4&3.
// ---------------------------------------------------------------------------
__global__ __launch_bounds__(256) void convertP(
    const float* __restrict__ src, ushortT* __restrict__ dst, int nElem4,
    long long rowsTotal, long long rowOff)
{
    int g = blockIdx.x * 256 + threadIdx.x;
    if (g >= nElem4) return;
    int row = g >> 8;            // 256 float4 per row
    int c4  = g & 255;           // float4 idx (k = c4*4)
    int p = c4 >> 2, o = c4 & 3;
    const float4 v = *(const float4*)(src + (size_t)row * DIM + c4 * 4);
    uint2 H, L;
    split4(v, H, L);
    ushortT* base = dst + (size_t)p * rowsTotal * 32 + (size_t)(rowOff + row) * 32;
    *(uint2*)(base + o * 4)      = H;
    *(uint2*)(base + 16 + o * 4) = L;
}

// ---------------------------------------------------------------------------
// convertA (chunk-major, fallback path only): rows x 1024 fp32 ->
//   ext rows x [32 chunks][32H|32L], row stride 2048 ushorts.
// ---------------------------------------------------------------------------
__global__ __launch_bounds__(256) void convertA(
    const float* __restrict__ src, ushortT* __restrict__ dst, int nElem4)
{
    int g = blockIdx.x * 256 + threadIdx.x;
    if (g >= nElem4) return;
    int row = g >> 8;
    int c4  = g & 255;
    int chunk = c4 >> 3, pos = c4 & 7;
    const float4 v = *(const float4*)(src + (size_t)row * DIM + c4 * 4);
    uint2 H, L;
    split4(v, H, L);
    ushortT* base = dst + (size_t)row * 2048 + chunk * 64;
    *(uint2*)(base + pos * 4)      = H;
    *(uint2*)(base + 32 + pos * 4) = L;
}

// ---------------------------------------------------------------------------
// Fused GEMM v6: 512 threads / 8 waves, block tile 256x512, wave tile 128x128.
// Phase-major ext staging (contiguous per phase), BK=16, 96KB dyn LDS dbuf,
// one drain barrier per phase after compute. XCD-aware swizzle.
// Grid (nn, 16), nn % 8 == 0. Global n-block = nb0 + bx:
//   [0,8)=qk, [8,16)=v, [16,32)=know.
// ---------------------------------------------------------------------------
__global__ __launch_bounds__(512, 2) void gemm_fused6(
    const ushortT* __restrict__ Aext, const ushortT* __restrict__ Bext,
    float* __restrict__ gQ, float* __restrict__ gV, float* __restrict__ gKn,
    int nb0, long long bRows)
{
    extern __shared__ ushortT lds[];   // 2 x (A 8192 + B 16384 shorts) = 96 KB
#define ABUF(b) (lds + (b) * 24576)
#define BBUF(b) (lds + (b) * 24576 + 8192)
    const int tid = threadIdx.x;
    const int wave = tid >> 6, lane = tid & 63;
    const int l32 = lane & 31, h = lane >> 5;
    const int wm = (wave >> 2) * 128;      // 2 waves in M (256)
    const int wn = (wave & 3) * 128;       // 4 waves in N (512)

    // XCD-aware bijective swizzle: consecutive lids round-robin XCDs; give
    // each XCD contiguous columns (bx fixed, by sweeping) for B-panel L2 reuse.
    const int lid = blockIdx.y * gridDim.x + blockIdx.x;
    const int xcd = lid & 7, s = lid >> 3;
    const int by = s & 15;                 // gridDim.y == 16
    const int bx = xcd + 8 * (s >> 4);     // gridDim.x % 8 == 0

    const long long m0 = (long long)by * 256;
    const int nblk = nb0 + bx;

    float* C; long long ldc; long long n0;
    if (nblk < 8)       { C = gQ;  ldc = N_QK;   n0 = (long long)nblk * 512; }
    else if (nblk < 16) { C = gV;  ldc = N_QK;   n0 = (long long)(nblk - 8) * 512; }
    else                { C = gKn; ldc = N_KNOW; n0 = (long long)(nblk - 16) * 512; }

    // staging: thread covers (row r4 = tid>>2, slot sl = tid&3) + it*128 rows.
    // LDS slot sl holds global seg sl ^ ((r>>1)&3); key reduces to (tid>>3)&3.
    const int sg = (tid & 3) ^ ((tid >> 3) & 3);
    const int r4 = tid >> 2;
    const long long apStride = (long long)M_ROWS * 32;   // shorts per phase block
    const long long bpStride = bRows * 32;
    const ushortT* gA0 = Aext + (m0 + r4) * 32 + sg * 8;
    const ushortT* gB0 = Bext + ((long long)bx * 512 + r4) * 32 + sg * 8;

    // read byte offset of my H seg within a row's 64B phase; L at so^32.
    const int so = (h ^ ((l32 >> 1) & 3)) * 16;

    f32x16 acc[4][4] = {};

#define STAGE(buf, cc) do {                                                        \
    const ushortT* _ga = gA0 + (long long)(cc) * apStride;                         \
    const ushortT* _gb = gB0 + (long long)(cc) * bpStride;                         \
    _Pragma("unroll")                                                              \
    for (int it = 0; it < 2; ++it)                                                 \
        __builtin_amdgcn_global_load_lds(                                          \
            (const __attribute__((address_space(1))) unsigned*)(const void*)(_ga + it * 4096), \
            (__attribute__((address_space(3))) unsigned*)(void*)(ABUF(buf) + tid * 8 + it * 4096), 16, 0, 0); \
    _Pragma("unroll")                                                              \
    for (int it = 0; it < 4; ++it)                                                 \
        __builtin_amdgcn_global_load_lds(                                          \
            (const __attribute__((address_space(1))) unsigned*)(const void*)(_gb + it * 4096), \
            (__attribute__((address_space(3))) unsigned*)(void*)(BBUF(buf) + tid * 8 + it * 4096), 16, 0, 0); \
} while (0)

#define COMPUTE(buf) do {                                                          \
    short8 aH[4], aL[4];                                                           \
    _Pragma("unroll")                                                              \
    for (int t = 0; t < 4; ++t) {                                                  \
        const char* pa = (const char*)ABUF(buf) + (wm + t * 32 + l32) * 64;        \
        aH[t] = *(const short8*)(pa + so);                                         \
        aL[t] = *(const short8*)(pa + (so ^ 32));                                  \
    }                                                                              \
    _Pragma("unroll")                                                              \
    for (int j = 0; j < 4; ++j) {                                                  \
        const char* pb = (const char*)BBUF(buf) + (wn + j * 32 + l32) * 64;        \
        short8 bH = *(const short8*)(pb + so);                                     \
        short8 bL = *(const short8*)(pb + (so ^ 32));                              \
        _Pragma("unroll")                                                          \
        for (int i = 0; i < 4; ++i) {                                              \
            acc[i][j] = __builtin_amdgcn_mfma_f32_32x32x16_bf16(aH[i], bH, acc[i][j], 0, 0, 0); \
            acc[i][j] = __builtin_amdgcn_mfma_f32_32x32x16_bf16(aH[i], bL, acc[i][j], 0, 0, 0); \
            acc[i][j] = __builtin_amdgcn_mfma_f32_32x32x16_bf16(aL[i], bH, acc[i][j], 0, 0, 0); \
            acc[i][j] = __builtin_amdgcn_mfma_f32_32x32x16_bf16(aL[i], bL, acc[i][j], 0, 0, 0); \
        }                                                                          \
    }                                                                              \
} while (0)

    // prologue: fill buf0 with phase 0
    STAGE(0, 0);
    __syncthreads();

    for (int cc = 0; cc < 64; cc += 2) {
        STAGE(1, cc + 1);             // prefetch next phase into other buffer
        COMPUTE(0);                   // 64 MFMAs/wave cover the DMA latency
        __syncthreads();              // drain AFTER compute
        if (cc + 2 < 64) STAGE(0, cc + 2);
        COMPUTE(1);
        __syncthreads();
    }
#undef STAGE
#undef COMPUTE
#undef ABUF
#undef BBUF

    // C/D: col=lane&31, row=(reg&3)+8*(reg>>2)+4*h  [m74/m101 verified]
#pragma unroll
    for (int ti = 0; ti < 4; ++ti)
#pragma unroll
        for (int tj = 0; tj < 4; ++tj) {
            long long col = n0 + wn + tj * 32 + l32;
            long long rb  = m0 + wm + ti * 32 + 4 * h;
#pragma unroll
            for (int reg = 0; reg < 16; ++reg) {
                long long row = rb + (reg & 3) + 8 * (reg >> 2);
                C[row * ldc + col] = acc[ti][tj][reg];
            }
        }
}

// ---------------------------------------------------------------------------
// OLD fused GEMM (fallback when ws cannot hold B_ext): unchanged, verified.
// ---------------------------------------------------------------------------
__global__ __launch_bounds__(256) void gemm_fused2(
    const ushortT* __restrict__ Aext, const float* __restrict__ qk_emb,
    const float* __restrict__ v_emb, const float* __restrict__ know_emb,
    float* __restrict__ gQ, float* __restrict__ gV, float* __restrict__ gKn,
    long long rowOff)
{
    __shared__ ushortT AHL[128 * 64];   // 128 rows x 128 B
    __shared__ ushortT BHL[128 * 64];
    const int tid = threadIdx.x;
    const int wave = tid >> 6, lane = tid & 63;
    const int l32 = lane & 31, h = lane >> 5;
    const int rx7 = l32 & 7;
    const int wm = (wave >> 1) * 64, wn = (wave & 1) * 64;
    const long long m0 = (long long)blockIdx.y * 128;
    const int nblk = blockIdx.x;

    const float* Bsrc; float* C; long long ldc; long long n0;
    if (nblk < 32)      { Bsrc = qk_emb;   C = gQ;  ldc = N_QK;   n0 = (long long)nblk * 128; }
    else if (nblk < 64) { Bsrc = v_emb;    C = gV;  ldc = N_QK;   n0 = (long long)(nblk - 32) * 128; }
    else                { Bsrc = know_emb; C = gKn; ldc = N_KNOW; n0 = (long long)(nblk - 64) * 128; }

    const ushortT* gAp[4]; ushortT* lAp[4];
    const float*   gBp[4]; int offH[4], offL[4];
#pragma unroll
    for (int it = 0; it < 4; ++it) {
        int f = it * 256 + tid;
        int r = f >> 3, sp = f & 7;
        int sg = sp ^ (r & 7);
        gAp[it] = Aext + (m0 + r) * 2048 + sg * 8;
        lAp[it] = AHL + f * 8;
        int c4 = f & 7;
        int s = c4 >> 1, hf = c4 & 1;
        offH[it] = r * 128 + ((s ^ (r & 7)) * 16) + hf * 8;
        offL[it] = r * 128 + (((4 | s) ^ (r & 7)) * 16) + hf * 8;
        gBp[it] = Bsrc + (n0 + r) * DIM + c4 * 4;
    }
    const char* pA[2]; const char* pB[2];
#pragma unroll
    for (int t = 0; t < 2; ++t) {
        pA[t] = (const char*)AHL + (wm + t * 32 + l32) * 128;
        pB[t] = (const char*)BHL + (wn + t * 32 + l32) * 128;
    }

    f32x16 acc[2][2] = {};
    float4 bufB[4];
#pragma unroll
    for (int it = 0; it < 4; ++it) bufB[it] = *(const float4*)(gBp[it]);

    for (int c = 0; c < 32; ++c) {
#pragma unroll
        for (int it = 0; it < 4; ++it) {
            __builtin_amdgcn_global_load_lds(
                (const __attribute__((address_space(1))) unsigned*)(const void*)(gAp[it] + c * 64),
                (__attribute__((address_space(3))) unsigned*)(void*)lAp[it], 16, 0, 0);
            uint2 H, L;
            split4(bufB[it], H, L);
            *(uint2*)((char*)BHL + offH[it]) = H;
            *(uint2*)((char*)BHL + offL[it]) = L;
        }
        __syncthreads();
        if (c + 1 < 32) {
#pragma unroll
            for (int it = 0; it < 4; ++it)
                bufB[it] = *(const float4*)(gBp[it] + (c + 1) * 32);
        }
#pragma unroll
        for (int kb = 0; kb < 2; ++kb) {
            const int so = ((kb * 2 + h) ^ rx7) * 16;
            short8 aH[2], aL[2], bH[2], bL[2];
#pragma unroll
            for (int t = 0; t < 2; ++t) {
                aH[t] = *(const short8*)(pA[t] + so);
                aL[t] = *(const short8*)(pA[t] + (so ^ 64));
                bH[t] = *(const short8*)(pB[t] + so);
                bL[t] = *(const short8*)(pB[t] + (so ^ 64));
            }
#pragma unroll
            for (int i = 0; i < 2; ++i)
#pragma unroll
                for (int j = 0; j < 2; ++j) {
                    acc[i][j] = __builtin_amdgcn_mfma_f32_32x32x16_bf16(aH[i], bH[j], acc[i][j], 0, 0, 0);
                    acc[i][j] = __builtin_amdgcn_mfma_f32_32x32x16_bf16(aH[i], bL[j], acc[i][j], 0, 0, 0);
                    acc[i][j] = __builtin_amdgcn_mfma_f32_32x32x16_bf16(aL[i], bH[j], acc[i][j], 0, 0, 0);
                    acc[i][j] = __builtin_amdgcn_mfma_f32_32x32x16_bf16(aL[i], bL[j], acc[i][j], 0, 0, 0);
                }
        }
        __syncthreads();
    }
#pragma unroll
    for (int ti = 0; ti < 2; ++ti)
#pragma unroll
        for (int tj = 0; tj < 2; ++tj) {
            long long col = n0 + wn + tj * 32 + l32;
            long long rb  = rowOff + m0 + wm + ti * 32 + 4 * h;
#pragma unroll
            for (int reg = 0; reg < 16; ++reg) {
                long long row = rb + (reg & 3) + 8 * (reg >> 2);
                C[row * ldc + col] = acc[ti][tj][reg];
            }
        }
}

// ---------------------------------------------------------------------------
// Gate body: keys in registers; exact k-th largest via 8-bit RADIX SELECT,
// with an exact pivot pre-filter (mu+2sigma; verified by exact count; falls
// back to unfiltered when count < k). Keys < pivot are all < kth, so the
// selected vk is EXACTLY the k-th largest key -> outputs bit-identical.
// ---------------------------------------------------------------------------
__device__ __forceinline__ unsigned floatToKey(float f) {
    unsigned b = __float_as_uint(f);
    return (b & 0x80000000u) ? ~b : (b | 0x80000000u);
}
__device__ __forceinline__ float keyToFloat(unsigned key) {
    unsigned b = (key & 0x80000000u) ? (key & 0x7FFFFFFFu) : ~key;
    return __uint_as_float(b);
}
__device__ __forceinline__ float egate(float raw) {
    float g = raw > 0.f ? raw : 1e-8f * __expf(raw);
    return expf(g) - 1.f;
}

template <int NV, bool VLOAD, bool VSTORE>
__device__ __forceinline__ void gate_body(
    const float* __restrict__ srow, float tA, float tB, bool hasB, int ksel,
    float* __restrict__ orowA, float* __restrict__ orowB,
    float* __restrict__ colA, float* __restrict__ colB,
    int* s_hist, unsigned* s_u, float* s_f)
{
    const int tid = threadIdx.x, lane = tid & 63, wv = tid >> 6;

    unsigned keys[NV * 4];
    unsigned kmax = 0u;
    float fs = 0.f, fq = 0.f;
#pragma unroll
    for (int i = 0; i < NV; i++) {
        float v0, v1, v2, v3;
        if (VLOAD) {
            float4 v = *(const float4*)(srow + (size_t)(i * 256 + tid) * 4);
            v0 = v.x; v1 = v.y; v2 = v.z; v3 = v.w;
        } else {
            v0 = srow[(i * 4 + 0) * 256 + tid];
            v1 = srow[(i * 4 + 1) * 256 + tid];
            v2 = srow[(i * 4 + 2) * 256 + tid];
            v3 = srow[(i * 4 + 3) * 256 + tid];
        }
        fs += v0 + v1 + v2 + v3;
        fq += v0 * v0 + v1 * v1 + v2 * v2 + v3 * v3;
        unsigned a = floatToKey(v0), b = floatToKey(v1);
        unsigned c = floatToKey(v2), d = floatToKey(v3);
        keys[i * 4 + 0] = a; keys[i * 4 + 1] = b;
        keys[i * 4 + 2] = c; keys[i * 4 + 3] = d;
        unsigned m1 = a > b ? a : b, m2 = c > d ? c : d;
        m1 = m1 > m2 ? m1 : m2;
        kmax = kmax > m1 ? kmax : m1;
    }
#pragma unroll
    for (int o = 32; o > 0; o >>= 1) {
        unsigned x = __shfl_down(kmax, o, 64);
        kmax = kmax > x ? kmax : x;
        fs += __shfl_down(fs, o, 64);
        fq += __shfl_down(fq, o, 64);
    }
    if (lane == 0) { s_u[wv] = kmax; s_f[wv] = fs; s_f[4 + wv] = fq; }
    __syncthreads();
    { unsigned a = s_u[0], b = s_u[1], c = s_u[2], d = s_u[3];
      unsigned m1 = a > b ? a : b, m2 = c > d ? c : d; kmax = m1 > m2 ? m1 : m2; }
    fs = s_f[0] + s_f[1] + s_f[2] + s_f[3];
    fq = s_f[4] + s_f[5] + s_f[6] + s_f[7];

    // exact pivot filter: piv = mu + 2*sigma (exact moments of this row)
    const float NT = (float)(NV * 4 * 256);
    const float mu = fs / NT;
    const float sd = sqrtf(fmaxf(fq / NT - mu * mu, 0.f));
    const unsigned pk = floatToKey(mu + 2.0f * sd);
    __syncthreads();                       // s_u/s_f reused below

    int pc = 0;
#pragma unroll
    for (int i = 0; i < NV * 4; i++) pc += (keys[i] >= pk) ? 1 : 0;
#pragma unroll
    for (int o = 32; o > 0; o >>= 1) pc += __shfl_down(pc, o, 64);
    if (lane == 0) s_u[wv] = (unsigned)pc;
    __syncthreads();
    const int ptot = (int)(s_u[0] + s_u[1] + s_u[2] + s_u[3]);
    const unsigned filt = (ptot >= ksel) ? pk : 0u;   // safe: filt <= kth key

    // ---- exact k-th largest key via 4-round radix select (filtered) ----
    unsigned prefix = 0u;
    int kk = ksel;
#pragma unroll
    for (int rnd = 0; rnd < 4; ++rnd) {
        const int sh = 24 - 8 * rnd;
        s_hist[tid] = 0;
        __syncthreads();
#pragma unroll
        for (int i = 0; i < NV * 4; i++) {
            unsigned key = keys[i];
            if (key >= filt && (((key ^ prefix) >> sh) >> 8) == 0u)
                atomicAdd(&s_hist[(key >> sh) & 255u], 1);
        }
        __syncthreads();
        if (tid < 64) {
            const int b3 = 255 - 4 * tid;          // lane covers bins b3-3..b3
            const int h0 = s_hist[b3],     h1 = s_hist[b3 - 1];
            const int h2 = s_hist[b3 - 2], h3 = s_hist[b3 - 3];
            const int gsum = h0 + h1 + h2 + h3;
            int inc = gsum;                         // inclusive scan, asc lane = desc bins
#pragma unroll
            for (int o = 1; o < 64; o <<= 1) {
                int v = __shfl_up(inc, o, 64);
                if (tid >= o) inc += v;
            }
            const int above = inc - gsum;           // keys in strictly higher bins
            const int c0 = above + h0, c1 = c0 + h1, c2 = c1 + h2, c3 = c2 + h3;
            if (kk > above && kk <= c3) {           // exactly one lane hits
                unsigned byt; int nk;
                if (kk <= c0)      { byt = (unsigned)b3;       nk = kk - above; }
                else if (kk <= c1) { byt = (unsigned)(b3 - 1); nk = kk - c0; }
                else if (kk <= c2) { byt = (unsigned)(b3 - 2); nk = kk - c1; }
                else               { byt = (unsigned)(b3 - 3); nk = kk - c2; }
                s_u[0] = byt; s_u[1] = (unsigned)nk;
            }
        }
        __syncthreads();
        prefix |= s_u[0] << sh;
        kk = (int)s_u[1];
    }
    const unsigned vk = prefix;                     // exact k-th largest key

    float sA = 0.f, sB = 0.f;
#pragma unroll
    for (int i = 0; i < NV * 4; i++) {
        if (keys[i] >= vk) {
            float s = keyToFloat(keys[i]);
            sA += egate(s - tA);
            if (hasB) sB += egate(s - tB);
        }
    }
#pragma unroll
    for (int o = 32; o > 0; o >>= 1) {
        sA += __shfl_down(sA, o, 64);
        sB += __shfl_down(sB, o, 64);
    }
    if (lane == 0) { s_f[wv] = sA; s_f[4 + wv] = sB; }
    __syncthreads();
    sA = s_f[0] + s_f[1] + s_f[2] + s_f[3];
    sB = s_f[4] + s_f[5] + s_f[6] + s_f[7];

    const float smax = keyToFloat(kmax);
    const float scaleA = tanhf(egate(smax - tA)) / (sA + 1e-8f);
    const float scaleB = hasB ? tanhf(egate(smax - tB)) / (sB + 1e-8f) : 0.f;

#pragma unroll
    for (int i = 0; i < NV; i++) {
        float ga[4], gb[4];
        int eidx[4];
#pragma unroll
        for (int j = 0; j < 4; j++) {
            int ii = i * 4 + j;
            int idx = VLOAD ? (i * 1024 + tid * 4 + j) : (ii * 256 + tid);
            eidx[j] = idx;
            unsigned key = keys[ii];
            float vA = 0.f, vB = 0.f;
            if (key >= vk) {
                float s = keyToFloat(key);
                vA = egate(s - tA) * scaleA;
                atomicAdd(&colA[idx], vA);
                if (hasB) { vB = egate(s - tB) * scaleB; atomicAdd(&colB[idx], vB); }
            }
            ga[j] = vA; gb[j] = vB;
        }
        if (VSTORE) {
            *(float4*)(orowA + (size_t)eidx[0]) = make_float4(ga[0], ga[1], ga[2], ga[3]);
            if (hasB) *(float4*)(orowB + (size_t)eidx[0]) = make_float4(gb[0], gb[1], gb[2], gb[3]);
        } else {
#pragma unroll
            for (int j = 0; j < 4; j++) {
                orowA[eidx[j]] = ga[j];
                if (hasB) orowB[eidx[j]] = gb[j];
            }
        }
    }
}

// Merged gate dispatch: [0,4096)=know, [4096,8192)=qk (Q+K), [8192,12288)=v
__global__ __launch_bounds__(256) void gate_all(
    const float* __restrict__ tau4,
    float* __restrict__ gQ, float* __restrict__ gK,
    float* __restrict__ gV, float* __restrict__ gKn,
    float* __restrict__ colsums)
{
    __shared__ int s_hist[256];
    __shared__ unsigned s_u[4];
    __shared__ float s_f[8];
    const int bid = blockIdx.x;
    if (bid < 4096) {
        const int row = bid;
        const float t = tau4[(size_t)row * 4 + 3];
        gate_body<8, false, false>(
            gKn + (size_t)row * N_KNOW, t, 0.f, false, 128,
            gKn + (size_t)row * N_KNOW, nullptr,
            colsums + 3 * N_QK, nullptr, s_hist, s_u, s_f);
    } else if (bid < 8192) {
        const int row = bid - 4096;
        const float tA = tau4[(size_t)row * 4 + 0];
        const float tB = tau4[(size_t)row * 4 + 1];
        gate_body<4, true, true>(
            gQ + (size_t)row * N_QK, tA, tB, true, 64,
            gQ + (size_t)row * N_QK, gK + (size_t)row * N_QK,
            colsums, colsums + N_QK, s_hist, s_u, s_f);
    } else {
        const int row = bid - 8192;
        const float t = tau4[(size_t)row * 4 + 2];
        gate_body<4, true, true>(
            gV + (size_t)row * N_QK, t, 0.f, false, 64,
            gV + (size_t)row * N_QK, nullptr,
            colsums + 2 * N_QK, nullptr, s_hist, s_u, s_f);
    }
}

// ---------------------------------------------------------------------------
// Aux kernel
// ---------------------------------------------------------------------------
__global__ __launch_bounds__(256) void aux_kernel(
    const float* __restrict__ colsum,
    float* __restrict__ auxAttn, float* __restrict__ auxKnow)
{
    __shared__ float s_a[4];
    __shared__ float s_b[4];
    const int tid = threadIdx.x;
    const int lane = tid & 63, wv = tid >> 6;
    const float invM = 1.f / 4096.f;

    float sa = 0.f;
    const float tqk = 1.f / 4096.f;
    for (int i = tid; i < 3 * N_QK; i += 256) {
        float m = colsum[i] * invM - tqk;
        sa += m * m;
    }
    float sk = 0.f;
    const float tkn = 1.f / 8192.f;
    for (int i = tid; i < N_KNOW; i += 256) {
        float m = colsum[3 * N_QK + i] * invM - tkn;
        sk += m * m;
    }
#pragma unroll
    for (int o = 32; o > 0; o >>= 1) {
        sa += __shfl_down(sa, o, 64);
        sk += __shfl_down(sk, o, 64);
    }
    if (lane == 0) { s_a[wv] = sa; s_b[wv] = sk; }
    __syncthreads();
    if (tid == 0) {
        auxAttn[0] = (s_a[0] + s_a[1] + s_a[2] + s_a[3]) * 4096.f;
        auxKnow[0] = (s_b[0] + s_b[1] + s_b[2] + s_b[3]) * 8192.f;
    }
}

// ---------------------------------------------------------------------------
// Host helpers: convert B rows [rowLo,rowHi) of the concatenated (qk|v|know)
// matrix into Bext (local row 0 = global row rowLo).
// ---------------------------------------------------------------------------
static void convert_b_rangeP(const float* qk, const float* v, const float* kn,
                             ushortT* Bext, long long rowLo, long long rowHi,
                             long long bRows, hipStream_t stream)
{
    struct Seg { const float* p; long long lo, hi; };
    Seg seg[3] = { {qk, 0, 4096}, {v, 4096, 8192}, {kn, 8192, 16384} };
    for (int i = 0; i < 3; ++i) {
        long long lo = rowLo > seg[i].lo ? rowLo : seg[i].lo;
        long long hi = rowHi < seg[i].hi ? rowHi : seg[i].hi;
        if (lo < hi) {
            int nel4 = (int)((hi - lo) * 256);
            convertP<<<(nel4 + 255) / 256, 256, 0, stream>>>(
                seg[i].p + (size_t)(lo - seg[i].lo) * DIM,
                Bext, nel4, bRows, lo - rowLo);
        }
    }
}

// ---------------------------------------------------------------------------
// Launch
// ---------------------------------------------------------------------------
extern "C" void kernel_launch(void* const* d_in, const int* in_sizes, int n_in,
                              void* d_out, int out_size, void* d_ws, size_t ws_size,
                              hipStream_t stream)
{
    const float* x        = (const float*)d_in[0];
    const float* qk_emb   = (const float*)d_in[1];
    const float* v_emb    = (const float*)d_in[2];
    const float* know_emb = (const float*)d_in[3];
    const float* w_attn   = (const float*)d_in[4];
    const float* b_attn   = (const float*)d_in[5];
    const float* w_know   = (const float*)d_in[6];
    const float* b_know   = (const float*)d_in[7];
    float* out = (float*)d_out;

    const long long M = M_ROWS;

    float* gQ   = out;
    float* gK   = gQ + (size_t)M * N_QK;
    float* gV   = gK + (size_t)M * N_QK;
    float* auxA = gV + (size_t)M * N_QK;
    float* gKn  = auxA + 1;                    // only 4-byte aligned: scalar path
    float* auxK = gKn + (size_t)M * N_KNOW;

    // ---- ws plan: [A_ext][B_ext...][tau4|colsums] ----
    const long long nColsum = 3 * N_QK + N_KNOW;
    const long long tail_bytes = (M * 4 + nColsum) * 4;
    long long tailStart = ((long long)ws_size - tail_bytes) & ~255LL;
    float* tau4 = (float*)((char*)d_ws + tailStart);
    float* colsums = tau4 + (size_t)M * 4;

    const long long rowB = 4096;               // ext bytes per row
    const long long aBytes = M * rowB;         // 16 MB for full A_ext

    hipMemsetAsync(colsums, 0, nColsum * sizeof(float), stream);
    tau_kernel<<<(int)M, 256, 0, stream>>>(x, w_attn, b_attn, w_know, b_know, tau4, DIM);

    // B_ext capacity in units of 512-row n-blocks (2 MB each), multiple of 8
    long long availB = tailStart - aBytes;
    long long nbc = availB > 0 ? availB / (512 * rowB) : 0;
    nbc &= ~7LL;
    if (nbc > 32) nbc = 32;

    if (nbc >= 8) {
        // ---- phase-major pre-split A and B, DMA-staged dbuf GEMM (v6) ----
        ushortT* A_ext = (ushortT*)d_ws;
        ushortT* B_ext = (ushortT*)((char*)d_ws + aBytes);
        convertP<<<(int)(M * 256 / 256), 256, 0, stream>>>(x, A_ext, (int)(M * 256), M, 0);
        for (long long nb0 = 0; nb0 < 32; nb0 += nbc) {
            long long nn = (32 - nb0 < nbc) ? (32 - nb0) : nbc;   // multiple of 8
            long long bRows = nn * 512;
            convert_b_rangeP(qk_emb, v_emb, know_emb, B_ext,
                             nb0 * 512, (nb0 + nn) * 512, bRows, stream);
            gemm_fused6<<<dim3((unsigned)nn, 16), 512, 98304, stream>>>(
                A_ext, B_ext, gQ, gV, gKn, (int)nb0, bRows);
        }
    } else {
        // ---- fallback: chunk-major A, B split in-kernel ----
        long long ra = (tailStart / rowB / 128) * 128;
        if (ra > M) ra = M;
        if (ra < 128) ra = 128;
        ushortT* A_ext = (ushortT*)d_ws;
        for (long long a0 = 0; a0 < M; a0 += ra) {
            long long ac = (M - a0 < ra) ? (M - a0) : ra;
            int nel4 = (int)(ac * 256);
            convertA<<<(nel4 + 255) / 256, 256, 0, stream>>>(x + a0 * DIM, A_ext, nel4);
            gemm_fused2<<<dim3(128, (unsigned)(ac / 128)), 256, 0, stream>>>(
                A_ext, qk_emb, v_emb, know_emb, gQ, gV, gKn, a0);
        }
    }

    gate_all<<<12288, 256, 0, stream>>>(tau4, gQ, gK, gV, gKn, colsums);

    aux_kernel<<<1, 256, 0, stream>>>(colsums, auxA, auxK);
}

// Round 7
// 956.080 us; speedup vs baseline: 4.4476x; 2.5661x over previous
//
#include <hip/hip_runtime.h>
#include <hip/hip_bf16.h>

// ---------------------------------------------------------------------------
// B=2,S=2048,D=1024; M=4096 rows. N_QK=N_V=4096, N_KNOW=8192.
// One fused GEMM over N=16384 (qk|v|know), bf16x4 split, 32x32x16 MFMA.
// Round 7 == round 6 resubmission (round-6 bench was an infra failure:
// "MI355X container failed twice"; kernel never measured. Hang-audit clean:
// satisfiable vmcnt waits, uniform barrier counts, correct visibility).
// Round-3 verified geometry (256x256 block tile, 8 waves, wave tile 128x64,
// acc[4][2], BK=32, chunk-major ext, 128KB dbuf LDS; 426us) + ONE change:
//   T4 counted vmcnt: prologue stages chunks 0,1; per chunk:
//   s_waitcnt vmcnt(8) (retire ONLY the older stage) -> s_barrier ->
//   COMPUTE -> s_barrier -> STAGE(chunk+2). Never drains to 0 in the loop.
//   Accumulation order unchanged -> scores BIT-IDENTICAL.
// Gates: pivot-filtered radix select (twice bit-verified).
// Fallback (ws too small): original chunk-major convertA + gemm_fused2.
// ---------------------------------------------------------------------------

#define M_ROWS 4096
#define DIM    1024
#define N_QK   4096
#define N_KNOW 8192

typedef unsigned short ushortT;
typedef __attribute__((ext_vector_type(8)))  short short8;   // 8 bf16 (4 VGPR)
typedef __attribute__((ext_vector_type(16))) float f32x16;

// ---------------------------------------------------------------------------
// tau kernel
// ---------------------------------------------------------------------------
__global__ __launch_bounds__(256) void tau_kernel(
    const float* __restrict__ x, const float* __restrict__ w_attn,
    const float* __restrict__ b_attn, const float* __restrict__ w_know,
    const float* __restrict__ b_know, float* __restrict__ tau4, int D)
{
    __shared__ float s_f[4][4];
    const int row = blockIdx.x;
    const int tid = threadIdx.x;
    const float* xr = x + (size_t)row * D;
    float p0 = 0.f, p1 = 0.f, p2 = 0.f, p3 = 0.f;
    for (int d = tid; d < D; d += 256) {
        float xv = xr[d];
        p0 += xv * w_attn[d * 3 + 0];
        p1 += xv * w_attn[d * 3 + 1];
        p2 += xv * w_attn[d * 3 + 2];
        p3 += xv * w_know[d];
    }
#pragma unroll
    for (int o = 32; o > 0; o >>= 1) {
        p0 += __shfl_down(p0, o, 64);
        p1 += __shfl_down(p1, o, 64);
        p2 += __shfl_down(p2, o, 64);
        p3 += __shfl_down(p3, o, 64);
    }
    const int lane = tid & 63, wv = tid >> 6;
    if (lane == 0) { s_f[wv][0] = p0; s_f[wv][1] = p1; s_f[wv][2] = p2; s_f[wv][3] = p3; }
    __syncthreads();
    if (tid < 4) {
        float v = s_f[0][tid] + s_f[1][tid] + s_f[2][tid] + s_f[3][tid];
        v += (tid < 3) ? b_attn[tid] : b_know[0];
        tau4[(size_t)row * 4 + tid] = v;
    }
}

// ---------------------------------------------------------------------------
// split4: one float4 -> 4 bf16 hi (8B) + 4 bf16 lo (8B). Bit-identical to
// previous rounds (__float2bfloat16 RNE; residual exact in fp32).
// ---------------------------------------------------------------------------
__device__ __forceinline__ void split4(const float4 v, uint2& H, uint2& L) {
    float vv[4] = {v.x, v.y, v.z, v.w};
    unsigned h[4], l[4];
#pragma unroll
    for (int i = 0; i < 4; i++) {
        __hip_bfloat16 hb = __float2bfloat16(vv[i]);
        float r = vv[i] - __bfloat162float(hb);
        __hip_bfloat16 lb = __float2bfloat16(r);
        h[i] = *(ushortT*)&hb;
        l[i] = *(ushortT*)&lb;
    }
    H.x = h[0] | (h[1] << 16); H.y = h[2] | (h[3] << 16);
    L.x = l[0] | (l[1] << 16); L.y = l[2] | (l[3] << 16);
}

// ---------------------------------------------------------------------------
// convertA: rows x 1024 fp32 -> ext rows x [32 chunks][32 H | 32 L] bf16
// Row stride 2048 ushorts (4 KB). One float4 per thread. Used for A and B.
// ---------------------------------------------------------------------------
__global__ __launch_bounds__(256) void convertA(
    const float* __restrict__ src, ushortT* __restrict__ dst, int nElem4)
{
    int g = blockIdx.x * 256 + threadIdx.x;
    if (g >= nElem4) return;
    int row = g >> 8;            // 256 float4 per row
    int c4  = g & 255;           // float4 idx
    int chunk = c4 >> 3, pos = c4 & 7;
    const float4 v = *(const float4*)(src + (size_t)row * DIM + c4 * 4);
    uint2 H, L;
    split4(v, H, L);
    ushortT* base = dst + (size_t)row * 2048 + chunk * 64;
    *(uint2*)(base + pos * 4)      = H;
    *(uint2*)(base + 32 + pos * 4) = L;
}

// ---------------------------------------------------------------------------
// Fused GEMM v4+T4: 512 threads / 8 waves, block tile 256x256, wave tile
// 128x64 (acc[4][2]), BK=32, 128KB dynamic LDS double-buffer.
// Counted-vmcnt pipeline: two stages in flight; per chunk wait vmcnt(8)
// (older stage only), s_barrier, COMPUTE, s_barrier, STAGE(chunk+2).
// Grid (nn, 16). Global n-block (256 cols) = nb0 + blockIdx.x:
//   [0,16)=qk, [16,32)=v, [32,64)=know.
// ---------------------------------------------------------------------------
__global__ __launch_bounds__(512, 2) void gemm_fused4(
    const ushortT* __restrict__ Aext, const ushortT* __restrict__ Bext,
    float* __restrict__ gQ, float* __restrict__ gV, float* __restrict__ gKn,
    int nb0)
{
    extern __shared__ ushortT lds[];   // [2][A:16384 | B:16384] ushorts = 128 KB
#define ABUF(b) (lds + (b) * 32768)
#define BBUF(b) (lds + (b) * 32768 + 16384)
    const int tid = threadIdx.x;
    const int wave = tid >> 6, lane = tid & 63;
    const int l32 = lane & 31, h = lane >> 5;
    const int rx7 = l32 & 7;
    const int wm = (wave >> 2) * 128;      // 2 waves in M
    const int wn = (wave & 3) * 64;        // 4 waves in N
    const long long m0 = (long long)blockIdx.y * 256;
    const int nblk = nb0 + blockIdx.x;

    float* C; long long ldc; long long n0;
    if (nblk < 16)      { C = gQ;  ldc = N_QK;   n0 = (long long)nblk * 256; }
    else if (nblk < 32) { C = gV;  ldc = N_QK;   n0 = (long long)(nblk - 16) * 256; }
    else                { C = gKn; ldc = N_KNOW; n0 = (long long)(nblk - 32) * 256; }

    // --- staging plans (identical seg-swizzle for A and B) ---
    const ushortT* gAp[4]; const ushortT* gBp[4]; int lOff[4];
#pragma unroll
    for (int it = 0; it < 4; ++it) {
        int f = it * 512 + tid;          // 0..2047 (256 rows x 8 segs)
        int r = f >> 3, sp = f & 7;
        int sg = sp ^ (r & 7);
        gAp[it] = Aext + (m0 + r) * 2048 + sg * 8;                       // + c*64 per chunk
        gBp[it] = Bext + ((long long)blockIdx.x * 256 + r) * 2048 + sg * 8;
        lOff[it] = f * 8;                                                // 16 B per slot
    }

    f32x16 acc[4][2] = {};

#define STAGE(buf, c) do {                                                         \
    _Pragma("unroll")                                                              \
    for (int it = 0; it < 4; ++it) {                                               \
        __builtin_amdgcn_global_load_lds(                                          \
            (const __attribute__((address_space(1))) unsigned*)(const void*)(gAp[it] + (c) * 64), \
            (__attribute__((address_space(3))) unsigned*)(void*)(ABUF(buf) + lOff[it]), 16, 0, 0); \
        __builtin_amdgcn_global_load_lds(                                          \
            (const __attribute__((address_space(1))) unsigned*)(const void*)(gBp[it] + (c) * 64), \
            (__attribute__((address_space(3))) unsigned*)(void*)(BBUF(buf) + lOff[it]), 16, 0, 0); \
    }                                                                              \
} while (0)

#define COMPUTE(buf) do {                                                          \
    _Pragma("unroll")                                                              \
    for (int kb = 0; kb < 2; ++kb) {                                               \
        const int so = ((kb * 2 + h) ^ rx7) * 16;                                  \
        short8 aH[4], aL[4], bH[2], bL[2];                                         \
        _Pragma("unroll")                                                          \
        for (int t = 0; t < 4; ++t) {                                              \
            const char* pa = (const char*)ABUF(buf) + (wm + t * 32 + l32) * 128;   \
            aH[t] = *(const short8*)(pa + so);                                     \
            aL[t] = *(const short8*)(pa + (so ^ 64));                              \
        }                                                                          \
        _Pragma("unroll")                                                          \
        for (int t = 0; t < 2; ++t) {                                              \
            const char* pb = (const char*)BBUF(buf) + (wn + t * 32 + l32) * 128;   \
            bH[t] = *(const short8*)(pb + so);                                     \
            bL[t] = *(const short8*)(pb + (so ^ 64));                              \
        }                                                                          \
        _Pragma("unroll")                                                          \
        for (int i = 0; i < 4; ++i)                                                \
            _Pragma("unroll")                                                      \
            for (int j = 0; j < 2; ++j) {                                          \
                acc[i][j] = __builtin_amdgcn_mfma_f32_32x32x16_bf16(aH[i], bH[j], acc[i][j], 0, 0, 0); \
                acc[i][j] = __builtin_amdgcn_mfma_f32_32x32x16_bf16(aH[i], bL[j], acc[i][j], 0, 0, 0); \
                acc[i][j] = __builtin_amdgcn_mfma_f32_32x32x16_bf16(aL[i], bH[j], acc[i][j], 0, 0, 0); \
                acc[i][j] = __builtin_amdgcn_mfma_f32_32x32x16_bf16(aL[i], bL[j], acc[i][j], 0, 0, 0); \
            }                                                                      \
    }                                                                              \
} while (0)

    // prologue: two stages in flight (chunks 0 and 1)
    STAGE(0, 0);
    STAGE(1, 1);

    for (int c = 0; c < 32; ++c) {
        // retire ONLY the older stage (8 loads); newer stage stays in flight
        if (c < 31) asm volatile("s_waitcnt vmcnt(8)" ::: "memory");
        else        asm volatile("s_waitcnt vmcnt(0)" ::: "memory");
        __builtin_amdgcn_s_barrier();          // all waves: stage c visible
        __builtin_amdgcn_sched_barrier(0);
        COMPUTE(c & 1);                        // 64 MFMAs/wave on buf (c&1)
        __builtin_amdgcn_s_barrier();          // all waves done reading buf
        __builtin_amdgcn_sched_barrier(0);
        if (c + 2 < 32) STAGE(c & 1, c + 2);   // refill freed buffer
    }
#undef STAGE
#undef COMPUTE
#undef ABUF
#undef BBUF

    // C/D: col=lane&31, row=(reg&3)+8*(reg>>2)+4*h  [m74/m101 verified]
#pragma unroll
    for (int ti = 0; ti < 4; ++ti)
#pragma unroll
        for (int tj = 0; tj < 2; ++tj) {
            long long col = n0 + wn + tj * 32 + l32;
            long long rb  = m0 + wm + ti * 32 + 4 * h;
#pragma unroll
            for (int reg = 0; reg < 16; ++reg) {
                long long row = rb + (reg & 3) + 8 * (reg >> 2);
                C[row * ldc + col] = acc[ti][tj][reg];
            }
        }
}

// ---------------------------------------------------------------------------
// OLD fused GEMM (fallback when ws cannot hold B_ext): unchanged, verified.
// ---------------------------------------------------------------------------
__global__ __launch_bounds__(256) void gemm_fused2(
    const ushortT* __restrict__ Aext, const float* __restrict__ qk_emb,
    const float* __restrict__ v_emb, const float* __restrict__ know_emb,
    float* __restrict__ gQ, float* __restrict__ gV, float* __restrict__ gKn,
    long long rowOff)
{
    __shared__ ushortT AHL[128 * 64];   // 128 rows x 128 B
    __shared__ ushortT BHL[128 * 64];
    const int tid = threadIdx.x;
    const int wave = tid >> 6, lane = tid & 63;
    const int l32 = lane & 31, h = lane >> 5;
    const int rx7 = l32 & 7;
    const int wm = (wave >> 1) * 64, wn = (wave & 1) * 64;
    const long long m0 = (long long)blockIdx.y * 128;
    const int nblk = blockIdx.x;

    const float* Bsrc; float* C; long long ldc; long long n0;
    if (nblk < 32)      { Bsrc = qk_emb;   C = gQ;  ldc = N_QK;   n0 = (long long)nblk * 128; }
    else if (nblk < 64) { Bsrc = v_emb;    C = gV;  ldc = N_QK;   n0 = (long long)(nblk - 32) * 128; }
    else                { Bsrc = know_emb; C = gKn; ldc = N_KNOW; n0 = (long long)(nblk - 64) * 128; }

    const ushortT* gAp[4]; ushortT* lAp[4];
    const float*   gBp[4]; int offH[4], offL[4];
#pragma unroll
    for (int it = 0; it < 4; ++it) {
        int f = it * 256 + tid;
        int r = f >> 3, sp = f & 7;
        int sg = sp ^ (r & 7);
        gAp[it] = Aext + (m0 + r) * 2048 + sg * 8;
        lAp[it] = AHL + f * 8;
        int c4 = f & 7;
        int s = c4 >> 1, hf = c4 & 1;
        offH[it] = r * 128 + ((s ^ (r & 7)) * 16) + hf * 8;
        offL[it] = r * 128 + (((4 | s) ^ (r & 7)) * 16) + hf * 8;
        gBp[it] = Bsrc + (n0 + r) * DIM + c4 * 4;
    }
    const char* pA[2]; const char* pB[2];
#pragma unroll
    for (int t = 0; t < 2; ++t) {
        pA[t] = (const char*)AHL + (wm + t * 32 + l32) * 128;
        pB[t] = (const char*)BHL + (wn + t * 32 + l32) * 128;
    }

    f32x16 acc[2][2] = {};
    float4 bufB[4];
#pragma unroll
    for (int it = 0; it < 4; ++it) bufB[it] = *(const float4*)(gBp[it]);

    for (int c = 0; c < 32; ++c) {
#pragma unroll
        for (int it = 0; it < 4; ++it) {
            __builtin_amdgcn_global_load_lds(
                (const __attribute__((address_space(1))) unsigned*)(const void*)(gAp[it] + c * 64),
                (__attribute__((address_space(3))) unsigned*)(void*)lAp[it], 16, 0, 0);
            uint2 H, L;
            split4(bufB[it], H, L);
            *(uint2*)((char*)BHL + offH[it]) = H;
            *(uint2*)((char*)BHL + offL[it]) = L;
        }
        __syncthreads();
        if (c + 1 < 32) {
#pragma unroll
            for (int it = 0; it < 4; ++it)
                bufB[it] = *(const float4*)(gBp[it] + (c + 1) * 32);
        }
#pragma unroll
        for (int kb = 0; kb < 2; ++kb) {
            const int so = ((kb * 2 + h) ^ rx7) * 16;
            short8 aH[2], aL[2], bH[2], bL[2];
#pragma unroll
            for (int t = 0; t < 2; ++t) {
                aH[t] = *(const short8*)(pA[t] + so);
                aL[t] = *(const short8*)(pA[t] + (so ^ 64));
                bH[t] = *(const short8*)(pB[t] + so);
                bL[t] = *(const short8*)(pB[t] + (so ^ 64));
            }
#pragma unroll
            for (int i = 0; i < 2; ++i)
#pragma unroll
                for (int j = 0; j < 2; ++j) {
                    acc[i][j] = __builtin_amdgcn_mfma_f32_32x32x16_bf16(aH[i], bH[j], acc[i][j], 0, 0, 0);
                    acc[i][j] = __builtin_amdgcn_mfma_f32_32x32x16_bf16(aH[i], bL[j], acc[i][j], 0, 0, 0);
                    acc[i][j] = __builtin_amdgcn_mfma_f32_32x32x16_bf16(aL[i], bH[j], acc[i][j], 0, 0, 0);
                    acc[i][j] = __builtin_amdgcn_mfma_f32_32x32x16_bf16(aL[i], bL[j], acc[i][j], 0, 0, 0);
                }
        }
        __syncthreads();
    }
#pragma unroll
    for (int ti = 0; ti < 2; ++ti)
#pragma unroll
        for (int tj = 0; tj < 2; ++tj) {
            long long col = n0 + wn + tj * 32 + l32;
            long long rb  = rowOff + m0 + wm + ti * 32 + 4 * h;
#pragma unroll
            for (int reg = 0; reg < 16; ++reg) {
                long long row = rb + (reg & 3) + 8 * (reg >> 2);
                C[row * ldc + col] = acc[ti][tj][reg];
            }
        }
}

// ---------------------------------------------------------------------------
// Gate body: keys in registers; exact k-th largest via 8-bit RADIX SELECT,
// with an exact pivot pre-filter (mu+2sigma; verified by exact count; falls
// back to unfiltered when count < k). Keys < pivot are all < kth, so the
// selected vk is EXACTLY the k-th largest key -> outputs bit-identical.
// ---------------------------------------------------------------------------
__device__ __forceinline__ unsigned floatToKey(float f) {
    unsigned b = __float_as_uint(f);
    return (b & 0x80000000u) ? ~b : (b | 0x80000000u);
}
__device__ __forceinline__ float keyToFloat(unsigned key) {
    unsigned b = (key & 0x80000000u) ? (key & 0x7FFFFFFFu) : ~key;
    return __uint_as_float(b);
}
__device__ __forceinline__ float egate(float raw) {
    float g = raw > 0.f ? raw : 1e-8f * __expf(raw);
    return expf(g) - 1.f;
}

template <int NV, bool VLOAD, bool VSTORE>
__device__ __forceinline__ void gate_body(
    const float* __restrict__ srow, float tA, float tB, bool hasB, int ksel,
    float* __restrict__ orowA, float* __restrict__ orowB,
    float* __restrict__ colA, float* __restrict__ colB,
    int* s_hist, unsigned* s_u, float* s_f)
{
    const int tid = threadIdx.x, lane = tid & 63, wv = tid >> 6;

    unsigned keys[NV * 4];
    unsigned kmax = 0u;
    float fs = 0.f, fq = 0.f;
#pragma unroll
    for (int i = 0; i < NV; i++) {
        float v0, v1, v2, v3;
        if (VLOAD) {
            float4 v = *(const float4*)(srow + (size_t)(i * 256 + tid) * 4);
            v0 = v.x; v1 = v.y; v2 = v.z; v3 = v.w;
        } else {
            v0 = srow[(i * 4 + 0) * 256 + tid];
            v1 = srow[(i * 4 + 1) * 256 + tid];
            v2 = srow[(i * 4 + 2) * 256 + tid];
            v3 = srow[(i * 4 + 3) * 256 + tid];
        }
        fs += v0 + v1 + v2 + v3;
        fq += v0 * v0 + v1 * v1 + v2 * v2 + v3 * v3;
        unsigned a = floatToKey(v0), b = floatToKey(v1);
        unsigned c = floatToKey(v2), d = floatToKey(v3);
        keys[i * 4 + 0] = a; keys[i * 4 + 1] = b;
        keys[i * 4 + 2] = c; keys[i * 4 + 3] = d;
        unsigned m1 = a > b ? a : b, m2 = c > d ? c : d;
        m1 = m1 > m2 ? m1 : m2;
        kmax = kmax > m1 ? kmax : m1;
    }
#pragma unroll
    for (int o = 32; o > 0; o >>= 1) {
        unsigned x = __shfl_down(kmax, o, 64);
        kmax = kmax > x ? kmax : x;
        fs += __shfl_down(fs, o, 64);
        fq += __shfl_down(fq, o, 64);
    }
    if (lane == 0) { s_u[wv] = kmax; s_f[wv] = fs; s_f[4 + wv] = fq; }
    __syncthreads();
    { unsigned a = s_u[0], b = s_u[1], c = s_u[2], d = s_u[3];
      unsigned m1 = a > b ? a : b, m2 = c > d ? c : d; kmax = m1 > m2 ? m1 : m2; }
    fs = s_f[0] + s_f[1] + s_f[2] + s_f[3];
    fq = s_f[4] + s_f[5] + s_f[6] + s_f[7];

    // exact pivot filter: piv = mu + 2*sigma (exact moments of this row)
    const float NT = (float)(NV * 4 * 256);
    const float mu = fs / NT;
    const float sd = sqrtf(fmaxf(fq / NT - mu * mu, 0.f));
    const unsigned pk = floatToKey(mu + 2.0f * sd);
    __syncthreads();                       // s_u/s_f reused below

    int pc = 0;
#pragma unroll
    for (int i = 0; i < NV * 4; i++) pc += (keys[i] >= pk) ? 1 : 0;
#pragma unroll
    for (int o = 32; o > 0; o >>= 1) pc += __shfl_down(pc, o, 64);
    if (lane == 0) s_u[wv] = (unsigned)pc;
    __syncthreads();
    const int ptot = (int)(s_u[0] + s_u[1] + s_u[2] + s_u[3]);
    const unsigned filt = (ptot >= ksel) ? pk : 0u;   // safe: filt <= kth key

    // ---- exact k-th largest key via 4-round radix select (filtered) ----
    unsigned prefix = 0u;
    int kk = ksel;
#pragma unroll
    for (int rnd = 0; rnd < 4; ++rnd) {
        const int sh = 24 - 8 * rnd;
        s_hist[tid] = 0;
        __syncthreads();
#pragma unroll
        for (int i = 0; i < NV * 4; i++) {
            unsigned key = keys[i];
            if (key >= filt && (((key ^ prefix) >> sh) >> 8) == 0u)
                atomicAdd(&s_hist[(key >> sh) & 255u], 1);
        }
        __syncthreads();
        if (tid < 64) {
            const int b3 = 255 - 4 * tid;          // lane covers bins b3-3..b3
            const int h0 = s_hist[b3],     h1 = s_hist[b3 - 1];
            const int h2 = s_hist[b3 - 2], h3 = s_hist[b3 - 3];
            const int gsum = h0 + h1 + h2 + h3;
            int inc = gsum;                         // inclusive scan, asc lane = desc bins
#pragma unroll
            for (int o = 1; o < 64; o <<= 1) {
                int v = __shfl_up(inc, o, 64);
                if (tid >= o) inc += v;
            }
            const int above = inc - gsum;           // keys in strictly higher bins
            const int c0 = above + h0, c1 = c0 + h1, c2 = c1 + h2, c3 = c2 + h3;
            if (kk > above && kk <= c3) {           // exactly one lane hits
                unsigned byt; int nk;
                if (kk <= c0)      { byt = (unsigned)b3;       nk = kk - above; }
                else if (kk <= c1) { byt = (unsigned)(b3 - 1); nk = kk - c0; }
                else if (kk <= c2) { byt = (unsigned)(b3 - 2); nk = kk - c1; }
                else               { byt = (unsigned)(b3 - 3); nk = kk - c2; }
                s_u[0] = byt; s_u[1] = (unsigned)nk;
            }
        }
        __syncthreads();
        prefix |= s_u[0] << sh;
        kk = (int)s_u[1];
    }
    const unsigned vk = prefix;                     // exact k-th largest key

    float sA = 0.f, sB = 0.f;
#pragma unroll
    for (int i = 0; i < NV * 4; i++) {
        if (keys[i] >= vk) {
            float s = keyToFloat(keys[i]);
            sA += egate(s - tA);
            if (hasB) sB += egate(s - tB);
        }
    }
#pragma unroll
    for (int o = 32; o > 0; o >>= 1) {
        sA += __shfl_down(sA, o, 64);
        sB += __shfl_down(sB, o, 64);
    }
    if (lane == 0) { s_f[wv] = sA; s_f[4 + wv] = sB; }
    __syncthreads();
    sA = s_f[0] + s_f[1] + s_f[2] + s_f[3];
    sB = s_f[4] + s_f[5] + s_f[6] + s_f[7];

    const float smax = keyToFloat(kmax);
    const float scaleA = tanhf(egate(smax - tA)) / (sA + 1e-8f);
    const float scaleB = hasB ? tanhf(egate(smax - tB)) / (sB + 1e-8f) : 0.f;

#pragma unroll
    for (int i = 0; i < NV; i++) {
        float ga[4], gb[4];
        int eidx[4];
#pragma unroll
        for (int j = 0; j < 4; j++) {
            int ii = i * 4 + j;
            int idx = VLOAD ? (i * 1024 + tid * 4 + j) : (ii * 256 + tid);
            eidx[j] = idx;
            unsigned key = keys[ii];
            float vA = 0.f, vB = 0.f;
            if (key >= vk) {
                float s = keyToFloat(key);
                vA = egate(s - tA) * scaleA;
                atomicAdd(&colA[idx], vA);
                if (hasB) { vB = egate(s - tB) * scaleB; atomicAdd(&colB[idx], vB); }
            }
            ga[j] = vA; gb[j] = vB;
        }
        if (VSTORE) {
            *(float4*)(orowA + (size_t)eidx[0]) = make_float4(ga[0], ga[1], ga[2], ga[3]);
            if (hasB) *(float4*)(orowB + (size_t)eidx[0]) = make_float4(gb[0], gb[1], gb[2], gb[3]);
        } else {
#pragma unroll
            for (int j = 0; j < 4; j++) {
                orowA[eidx[j]] = ga[j];
                if (hasB) orowB[eidx[j]] = gb[j];
            }
        }
    }
}

// Merged gate dispatch: [0,4096)=know, [4096,8192)=qk (Q+K), [8192,12288)=v
__global__ __launch_bounds__(256) void gate_all(
    const float* __restrict__ tau4,
    float* __restrict__ gQ, float* __restrict__ gK,
    float* __restrict__ gV, float* __restrict__ gKn,
    float* __restrict__ colsums)
{
    __shared__ int s_hist[256];
    __shared__ unsigned s_u[4];
    __shared__ float s_f[8];
    const int bid = blockIdx.x;
    if (bid < 4096) {
        const int row = bid;
        const float t = tau4[(size_t)row * 4 + 3];
        gate_body<8, false, false>(
            gKn + (size_t)row * N_KNOW, t, 0.f, false, 128,
            gKn + (size_t)row * N_KNOW, nullptr,
            colsums + 3 * N_QK, nullptr, s_hist, s_u, s_f);
    } else if (bid < 8192) {
        const int row = bid - 4096;
        const float tA = tau4[(size_t)row * 4 + 0];
        const float tB = tau4[(size_t)row * 4 + 1];
        gate_body<4, true, true>(
            gQ + (size_t)row * N_QK, tA, tB, true, 64,
            gQ + (size_t)row * N_QK, gK + (size_t)row * N_QK,
            colsums, colsums + N_QK, s_hist, s_u, s_f);
    } else {
        const int row = bid - 8192;
        const float t = tau4[(size_t)row * 4 + 2];
        gate_body<4, true, true>(
            gV + (size_t)row * N_QK, t, 0.f, false, 64,
            gV + (size_t)row * N_QK, nullptr,
            colsums + 2 * N_QK, nullptr, s_hist, s_u, s_f);
    }
}

// ---------------------------------------------------------------------------
// Aux kernel
// ---------------------------------------------------------------------------
__global__ __launch_bounds__(256) void aux_kernel(
    const float* __restrict__ colsum,
    float* __restrict__ auxAttn, float* __restrict__ auxKnow)
{
    __shared__ float s_a[4];
    __shared__ float s_b[4];
    const int tid = threadIdx.x;
    const int lane = tid & 63, wv = tid >> 6;
    const float invM = 1.f / 4096.f;

    float sa = 0.f;
    const float tqk = 1.f / 4096.f;
    for (int i = tid; i < 3 * N_QK; i += 256) {
        float m = colsum[i] * invM - tqk;
        sa += m * m;
    }
    float sk = 0.f;
    const float tkn = 1.f / 8192.f;
    for (int i = tid; i < N_KNOW; i += 256) {
        float m = colsum[3 * N_QK + i] * invM - tkn;
        sk += m * m;
    }
#pragma unroll
    for (int o = 32; o > 0; o >>= 1) {
        sa += __shfl_down(sa, o, 64);
        sk += __shfl_down(sk, o, 64);
    }
    if (lane == 0) { s_a[wv] = sa; s_b[wv] = sk; }
    __syncthreads();
    if (tid == 0) {
        auxAttn[0] = (s_a[0] + s_a[1] + s_a[2] + s_a[3]) * 4096.f;
        auxKnow[0] = (s_b[0] + s_b[1] + s_b[2] + s_b[3]) * 8192.f;
    }
}

// ---------------------------------------------------------------------------
// Host helper: convert B rows [rowLo,rowHi) of the concatenated (qk|v|know)
// matrix into Bext (local row 0 = global row rowLo).
// ---------------------------------------------------------------------------
static void convert_b_range(const float* qk, const float* v, const float* kn,
                            ushortT* Bext, long long rowLo, long long rowHi,
                            hipStream_t stream)
{
    struct Seg { const float* p; long long lo, hi; };
    Seg seg[3] = { {qk, 0, 4096}, {v, 4096, 8192}, {kn, 8192, 16384} };
    for (int i = 0; i < 3; ++i) {
        long long lo = rowLo > seg[i].lo ? rowLo : seg[i].lo;
        long long hi = rowHi < seg[i].hi ? rowHi : seg[i].hi;
        if (lo < hi) {
            int nel4 = (int)((hi - lo) * 256);
            convertA<<<(nel4 + 255) / 256, 256, 0, stream>>>(
                seg[i].p + (size_t)(lo - seg[i].lo) * DIM,
                Bext + (size_t)(lo - rowLo) * 2048, nel4);
        }
    }
}

// ---------------------------------------------------------------------------
// Launch
// ---------------------------------------------------------------------------
extern "C" void kernel_launch(void* const* d_in, const int* in_sizes, int n_in,
                              void* d_out, int out_size, void* d_ws, size_t ws_size,
                              hipStream_t stream)
{
    const float* x        = (const float*)d_in[0];
    const float* qk_emb   = (const float*)d_in[1];
    const float* v_emb    = (const float*)d_in[2];
    const float* know_emb = (const float*)d_in[3];
    const float* w_attn   = (const float*)d_in[4];
    const float* b_attn   = (const float*)d_in[5];
    const float* w_know   = (const float*)d_in[6];
    const float* b_know   = (const float*)d_in[7];
    float* out = (float*)d_out;

    const long long M = M_ROWS;

    float* gQ   = out;
    float* gK   = gQ + (size_t)M * N_QK;
    float* gV   = gK + (size_t)M * N_QK;
    float* auxA = gV + (size_t)M * N_QK;
    float* gKn  = auxA + 1;                    // only 4-byte aligned: scalar path
    float* auxK = gKn + (size_t)M * N_KNOW;

    // ---- ws plan: [A_ext][B_ext...][tau4|colsums] ----
    const long long nColsum = 3 * N_QK + N_KNOW;
    const long long tail_bytes = (M * 4 + nColsum) * 4;
    long long tailStart = ((long long)ws_size - tail_bytes) & ~255LL;
    float* tau4 = (float*)((char*)d_ws + tailStart);
    float* colsums = tau4 + (size_t)M * 4;

    const long long rowB = 4096;               // ext bytes per row
    const long long aBytes = M * rowB;         // 16 MB for full A_ext

    hipMemsetAsync(colsums, 0, nColsum * sizeof(float), stream);
    tau_kernel<<<(int)M, 256, 0, stream>>>(x, w_attn, b_attn, w_know, b_know, tau4, DIM);

    // B_ext capacity in units of 256-row n-blocks (1 MB each)
    long long availB = tailStart - aBytes;
    long long nbc = availB > 0 ? availB / (256 * rowB) : 0;
    if (nbc > 64) nbc = 64;

    if (nbc >= 16) {
        // ---- pre-split A and B, DMA-staged counted-vmcnt GEMM (v4+T4) ----
        ushortT* A_ext = (ushortT*)d_ws;
        ushortT* B_ext = (ushortT*)((char*)d_ws + aBytes);
        convertA<<<(int)(M * 256 / 256), 256, 0, stream>>>(x, A_ext, (int)(M * 256));
        for (long long nb0 = 0; nb0 < 64; nb0 += nbc) {
            long long nn = (64 - nb0 < nbc) ? (64 - nb0) : nbc;
            convert_b_range(qk_emb, v_emb, know_emb, B_ext,
                            nb0 * 256, (nb0 + nn) * 256, stream);
            gemm_fused4<<<dim3((unsigned)nn, 16), 512, 131072, stream>>>(
                A_ext, B_ext, gQ, gV, gKn, (int)nb0);
        }
    } else {
        // ---- fallback: A chunked, B split in-kernel ----
        long long ra = (tailStart / rowB / 128) * 128;
        if (ra > M) ra = M;
        if (ra < 128) ra = 128;
        ushortT* A_ext = (ushortT*)d_ws;
        for (long long a0 = 0; a0 < M; a0 += ra) {
            long long ac = (M - a0 < ra) ? (M - a0) : ra;
            int nel4 = (int)(ac * 256);
            convertA<<<(nel4 + 255) / 256, 256, 0, stream>>>(x + a0 * DIM, A_ext, nel4);
            gemm_fused2<<<dim3(128, (unsigned)(ac / 128)), 256, 0, stream>>>(
                A_ext, qk_emb, v_emb, know_emb, gQ, gV, gKn, a0);
        }
    }

    gate_all<<<12288, 256, 0, stream>>>(tau4, gQ, gK, gV, gKn, colsums);

    aux_kernel<<<1, 256, 0, stream>>>(colsums, auxA, auxK);
}